// Round 2
// baseline (10277.078 us; speedup 1.0000x reference)
//
#include <hip/hip_runtime.h>

namespace {

constexpr int kB = 4, kN = 60000, kS = 1024, kV = 8, kD = 256, kH = 4, kDepth = 4, kC = 20;
constexpr int kDH = 64;           // D / H
constexpr int kMH = 1024;         // 4*D
constexpr int kTV = kC + kV;      // 28 view tokens
constexpr int kTX = kC + kS;      // 1044 vox tokens
constexpr float kScale = 0.125f;  // 1/sqrt(64)

constexpr int NSLICE = 8;         // slices over N for segment sum
constexpr int DC = 16;            // dims per segsum block (64B/point -> coalesced)
constexpr int DCH = kD / DC;      // 16 d-chunks

// ---------------------------------------------------------------------------
// Generic tiled fp32 GEMM: C[M,N] = act(alpha * A@B + bias) + Res
//   batched over gridDim.z with separate (batch, head) strides.
//   TRB: B element (k,n) read as Bm[n*ldb + k]  (used for Q @ K^T)
//   PRELU: relu applied to A elements on load (used for relu(vox)@head3d_w)
// Microtile is STRIDED: thread (tx,ty) owns cols {tx + j*16}, rows {ty + i*16}
//   -> B-fragment LDS reads hit 16 consecutive banks (conflict-free),
//      A-fragment reads are ty-broadcast, C stores stay 64B-coalesced.
// ---------------------------------------------------------------------------
template <int BM, int BN, int TM, int TN, int ACT, bool TRB, bool PRELU>
__global__ __launch_bounds__(256) void gemm_k(
    const float* __restrict__ A, const float* __restrict__ Bm,
    const float* __restrict__ bias, const float* __restrict__ Res,
    float* __restrict__ C, int M, int N, int K, int lda, int ldb, int ldc,
    long sAb, long sAh, long sBb, long sBh, long sCb, long sCh, int Hdim, float alpha)
{
  constexpr int KT = 16;
  constexpr int AE = BM * KT / 256;
  constexpr int BE = BN * KT / 256;
  __shared__ float As[KT][BM + 1];
  __shared__ float Bs[KT][BN + 1];
  const int z = blockIdx.z;
  const int bi = z / Hdim, hi = z - bi * Hdim;
  A += (long)bi * sAb + (long)hi * sAh;
  Bm += (long)bi * sBb + (long)hi * sBh;
  C += (long)bi * sCb + (long)hi * sCh;
  const float* R = Res;
  if (R) R += (long)bi * sCb + (long)hi * sCh;
  const int n0 = blockIdx.x * BN, m0 = blockIdx.y * BM;
  const int tid = threadIdx.x;
  const int tx = tid % 16, ty = tid / 16;
  float acc[TM][TN];
#pragma unroll
  for (int i = 0; i < TM; i++)
#pragma unroll
    for (int j = 0; j < TN; j++) acc[i][j] = 0.f;

  for (int k0 = 0; k0 < K; k0 += KT) {
#pragma unroll
    for (int i = 0; i < AE; i++) {
      int e = tid + i * 256;
      int row = e >> 4, kk = e & 15;
      int gm = m0 + row, gk = k0 + kk;
      float v = 0.f;
      if (gm < M && gk < K) v = A[(long)gm * lda + gk];
      if (PRELU) v = fmaxf(v, 0.f);
      As[kk][row] = v;
    }
#pragma unroll
    for (int i = 0; i < BE; i++) {
      int e = tid + i * 256;
      int kk, col;
      if (TRB) { kk = e & 15; col = e >> 4; }
      else     { col = e % BN; kk = e / BN; }
      int gk = k0 + kk, gn = n0 + col;
      float v = 0.f;
      if (gk < K && gn < N) v = TRB ? Bm[(long)gn * ldb + gk] : Bm[(long)gk * ldb + gn];
      Bs[kk][col] = v;
    }
    __syncthreads();
#pragma unroll
    for (int kk = 0; kk < KT; kk++) {
      float av[TM], bv[TN];
#pragma unroll
      for (int i = 0; i < TM; i++) av[i] = As[kk][ty + i * 16];
#pragma unroll
      for (int j = 0; j < TN; j++) bv[j] = Bs[kk][tx + j * 16];
#pragma unroll
      for (int i = 0; i < TM; i++)
#pragma unroll
        for (int j = 0; j < TN; j++) acc[i][j] += av[i] * bv[j];
    }
    __syncthreads();
  }
#pragma unroll
  for (int i = 0; i < TM; i++) {
    int gm = m0 + ty + i * 16;
    if (gm >= M) continue;
#pragma unroll
    for (int j = 0; j < TN; j++) {
      int gn = n0 + tx + j * 16;
      if (gn >= N) continue;
      float v = acc[i][j] * alpha;
      if (bias) v += bias[gn];
      if (ACT == 1) v = fmaxf(v, 0.f);
      else if (ACT == 2) {
        float u = v;
        v = 0.5f * u * (1.f + tanhf(0.7978845608028654f * (u + 0.044715f * u * u * u)));
      }
      if (R) v += R[(long)gm * ldc + gn];
      C[(long)gm * ldc + gn] = v;
    }
  }
}

// ---------------- LayerNorm over D=256, one block per row -----------------
__global__ __launch_bounds__(256) void ln_k(const float* __restrict__ x,
                                            const float* __restrict__ g,
                                            const float* __restrict__ b,
                                            float* __restrict__ o, int rows)
{
  __shared__ float red[256];
  __shared__ float stat;
  int row = blockIdx.x;
  int t = threadIdx.x;
  float v = x[(long)row * kD + t];
  red[t] = v;
  __syncthreads();
  for (int s = 128; s > 0; s >>= 1) { if (t < s) red[t] += red[t + s]; __syncthreads(); }
  if (t == 0) stat = red[0] * (1.f / kD);
  __syncthreads();
  float m = stat;
  float d = v - m;
  red[t] = d * d;
  __syncthreads();
  for (int s = 128; s > 0; s >>= 1) { if (t < s) red[t] += red[t + s]; __syncthreads(); }
  if (t == 0) stat = rsqrtf(red[0] * (1.f / kD) + 1e-5f);
  __syncthreads();
  o[(long)row * kD + t] = g[t] * d * stat + b[t];
}

// ---------------- row softmax (in place), one block per row ----------------
__global__ __launch_bounds__(256) void softmax_k(float* __restrict__ s, int L)
{
  long row = blockIdx.x;
  float* p = s + row * (long)L;
  int t = threadIdx.x;
  float rv[8];
  int nc = (L + 255) >> 8;
  float mx = -1e30f;
  for (int c = 0; c < nc; c++) {
    int i = t + c * 256;
    rv[c] = (i < L) ? p[i] : -1e30f;
    mx = fmaxf(mx, rv[c]);
  }
  __shared__ float red[256];
  __shared__ float bb;
  red[t] = mx; __syncthreads();
  for (int st = 128; st > 0; st >>= 1) { if (t < st) red[t] = fmaxf(red[t], red[t + st]); __syncthreads(); }
  if (t == 0) bb = red[0];
  __syncthreads();
  float bm = bb;
  float sum = 0.f;
  for (int c = 0; c < nc; c++) {
    int i = t + c * 256;
    if (i < L) { rv[c] = expf(rv[c] - bm); sum += rv[c]; }
  }
  red[t] = sum; __syncthreads();
  for (int st = 128; st > 0; st >>= 1) { if (t < st) red[t] += red[t + st]; __syncthreads(); }
  if (t == 0) bb = 1.f / red[0];
  __syncthreads();
  float inv = bb;
  for (int c = 0; c < nc; c++) {
    int i = t + c * 256;
    if (i < L) p[i] = rv[c] * inv;
  }
}

// ---------------- segment sum of point_feat via LDS (64KB) ----------------
__global__ __launch_bounds__(256) void segsum_k(const float* __restrict__ pf,
                                                const int* __restrict__ sv,
                                                float* __restrict__ part)
{
  __shared__ float acc[kS * DC];  // 65536 B
  int t = threadIdx.x;
  for (int i = t; i < kS * DC; i += 256) acc[i] = 0.f;
  __syncthreads();
  int dc = blockIdx.x, sl = blockIdx.y, b = blockIdx.z;
  const int per = kN / NSLICE;
  int n0 = sl * per, n1 = n0 + per;
  int ld_ = t & (DC - 1), pg = t >> 4;
  for (int n = n0 + pg; n < n1; n += 16) {
    int s = sv[b * kN + n];
    float v = pf[((long)b * kN + n) * kD + dc * DC + ld_];
    atomicAdd(&acc[s * DC + ld_], v);
  }
  __syncthreads();
  float* outp = part + (((long)(b * NSLICE + sl) * DCH + dc) * (kS * DC));
  for (int i = t; i < kS * DC; i += 256) outp[i] = acc[i];
}

__global__ __launch_bounds__(256) void segcnt_k(const int* __restrict__ sv,
                                                float* __restrict__ cpart)
{
  __shared__ float cnt[kS];
  int t = threadIdx.x;
  for (int i = t; i < kS; i += 256) cnt[i] = 0.f;
  __syncthreads();
  int sl = blockIdx.x, b = blockIdx.y;
  const int per = kN / NSLICE;
  int n0 = sl * per, n1 = n0 + per;
  for (int n = n0 + t; n < n1; n += 256) atomicAdd(&cnt[sv[b * kN + n]], 1.f);
  __syncthreads();
  float* outp = cpart + (long)(b * NSLICE + sl) * kS;
  for (int i = t; i < kS; i += 256) outp[i] = cnt[i];
}

__global__ void cntfin_k(const float* __restrict__ cpart, float* __restrict__ counts)
{
  int i = blockIdx.x * 256 + threadIdx.x;
  if (i >= kB * kS) return;
  int b = i / kS, s = i - b * kS;
  float c = 0.f;
  for (int sl = 0; sl < NSLICE; sl++) c += cpart[(long)(b * NSLICE + sl) * kS + s];
  counts[i] = c;
}

__global__ void poolfin_k(const float* __restrict__ part, const float* __restrict__ counts,
                          float* __restrict__ pooled)
{
  long i = (long)blockIdx.x * 256 + threadIdx.x;
  if (i >= (long)kB * kS * kD) return;
  int d = (int)(i % kD);
  long bs = i / kD;
  int s = (int)(bs % kS), b = (int)(bs / kS);
  int dc = d / DC, dl = d - dc * DC;
  float sum = 0.f;
  for (int sl = 0; sl < NSLICE; sl++)
    sum += part[(((long)(b * NSLICE + sl) * DCH + dc) * (kS * DC)) + s * DC + dl];
  float c = counts[b * kS + s];
  pooled[i] = (c > 0.5f) ? sum / c : 0.f;
}

__global__ void coordsum_k(const float* __restrict__ pc, const int* __restrict__ sv,
                           float* __restrict__ csum)
{
  int i = blockIdx.x * 256 + threadIdx.x;
  if (i >= kB * kN) return;
  int b = i / kN;
  int s = sv[i];
  for (int j = 0; j < 3; j++)
    atomicAdd(&csum[((long)b * kS + s) * 3 + j], pc[(long)i * 3 + j]);
}

__global__ void coordfin_k(const float* __restrict__ csum, const float* __restrict__ counts,
                           float* __restrict__ pcoord)
{
  int i = blockIdx.x * 256 + threadIdx.x;
  if (i >= kB * kS * 3) return;
  int bs = i / 3;
  float c = counts[bs];
  pcoord[i] = (c > 0.5f) ? csum[i] / c : 0.f;
}

// ---------------- consistency loss: mean((pf - pooled[sv])^2) --------------
__global__ __launch_bounds__(256) void closs_k(const float* __restrict__ pf,
                                               const int* __restrict__ sv,
                                               const float* __restrict__ pooled,
                                               float* __restrict__ outp)
{
  const long total = (long)kB * kN * (kD / 4);
  float a = 0.f;
  for (long i = (long)blockIdx.x * 256 + threadIdx.x; i < total; i += (long)gridDim.x * 256) {
    long pnt = i >> 6;
    int dc = (int)(i & 63);
    int b = (int)(pnt / kN);
    int s = sv[pnt];
    float4 v = ((const float4*)pf)[i];
    float4 m = ((const float4*)pooled)[((long)b * kS + s) * (kD / 4) + dc];
    float dx = v.x - m.x, dy = v.y - m.y, dz = v.z - m.z, dw = v.w - m.w;
    a += dx * dx + dy * dy + dz * dz + dw * dw;
  }
  __shared__ float red[256];
  red[threadIdx.x] = a; __syncthreads();
  for (int s = 128; s > 0; s >>= 1) { if (threadIdx.x < s) red[threadIdx.x] += red[threadIdx.x + s]; __syncthreads(); }
  if (threadIdx.x == 0) atomicAdd(outp, red[0]);
}

// ---------------- token build: cls+pos || tok+pos --------------------------
__global__ void build_k(const float* __restrict__ cls, const float* __restrict__ clspos,
                        const float* __restrict__ tok, const float* __restrict__ pos,
                        float* __restrict__ x, int T, int Tt, int posBatched)
{
  long i = (long)blockIdx.x * 256 + threadIdx.x;
  long tot = (long)kB * T * kD;
  if (i >= tot) return;
  int d = (int)(i % kD);
  long bt = i / kD;
  int t = (int)(bt % T), b = (int)(bt / T);
  float v;
  if (t < kC) v = cls[t * kD + d] + clspos[t * kD + d];
  else {
    int tt = t - kC;
    v = tok[((long)b * Tt + tt) * kD + d] +
        pos[((long)(posBatched ? b * Tt : 0) + tt) * kD + d];
  }
  x[i] = v;
}

// ---------------- token-sim loss from MHA1 probs (B,H,28,1044) -------------
__global__ __launch_bounds__(64) void simloss_k(const float* __restrict__ probs,
                                                float* __restrict__ accum)
{
  int b = blockIdx.x;
  __shared__ float sim[kC][kC];
  int t = threadIdx.x;
  for (int e = t; e < kC * kC; e += 64) {
    int i = e / kC, j = e - i * kC;
    float s = 0.f;
    for (int h = 0; h < kH; h++)
      s += probs[(((long)(b * kH + h)) * kTV + i) * kTX + j];
    sim[i][j] = s * (1.f / kH);
  }
  __syncthreads();
  float local = 0.f;
  if (t < kC) {
    int i = t;
    float mx = -1e30f;
    for (int j = 0; j < kC; j++) mx = fmaxf(mx, sim[i][j]);
    float se = 0.f;
    for (int j = 0; j < kC; j++) se += expf(sim[i][j] - mx);
    float dr = sim[i][i] - mx - logf(se);
    float mc = -1e30f;
    for (int j = 0; j < kC; j++) mc = fmaxf(mc, sim[j][i]);
    float sc = 0.f;
    for (int j = 0; j < kC; j++) sc += expf(sim[j][i] - mc);
    float dcl = sim[i][i] - mc - logf(sc);
    local = dr + dcl;
  }
  for (int o = 32; o > 0; o >>= 1) local += __shfl_down(local, o);
  if (t == 0) atomicAdd(accum, local * (-0.5f / kC));
}

// ---------------- small output kernels -------------------------------------
__global__ __launch_bounds__(64) void meanD_k(const float* __restrict__ x,
                                              float* __restrict__ o, int T)
{
  int bc = blockIdx.x;
  int b = bc / kC, c = bc - b * kC;
  const float* r = x + ((long)b * T + c) * kD;
  float s = 0.f;
  for (int d = threadIdx.x; d < kD; d += 64) s += r[d];
  for (int w = 32; w > 0; w >>= 1) s += __shfl_down(s, w);
  if (threadIdx.x == 0) o[bc] = s * (1.f / kD);
}

__global__ __launch_bounds__(64) void cross_k(const float* __restrict__ xv,
                                              const float* __restrict__ xw,
                                              float* __restrict__ o)
{
  int bc = blockIdx.x;
  int b = bc / kC, c = bc - b * kC;
  const float* rv = xv + ((long)b * kTX + c) * kD;
  const float* rw = xw + ((long)b * kTV + c) * kD;
  float s = 0.f;
  for (int d = threadIdx.x; d < kD; d += 64) s += 0.5f * (rv[d] + rw[d]);
  for (int w = 32; w > 0; w >>= 1) s += __shfl_down(s, w);
  if (threadIdx.x == 0) o[bc] = s * (1.f / kD);
}

__global__ __launch_bounds__(256) void cam3d_k(const float* __restrict__ vc,
                                               float* __restrict__ o)
{
  __shared__ float red[256];
  int bc = blockIdx.x;
  int b = bc / kC, c = bc - b * kC;
  float s = 0.f;
  for (int t = threadIdx.x; t < kS; t += 256) s += vc[((long)b * kS + t) * kC + c];
  red[threadIdx.x] = s; __syncthreads();
  for (int st = 128; st > 0; st >>= 1) { if (threadIdx.x < st) red[threadIdx.x] += red[threadIdx.x + st]; __syncthreads(); }
  if (threadIdx.x == 0) o[bc] = red[0] * (1.f / kS);
}

__global__ void meanv_k(const float* __restrict__ ivt, float* __restrict__ mv)
{
  int i = blockIdx.x * 256 + threadIdx.x;
  if (i >= kB * kD) return;
  int b = i / kD, d = i - b * kD;
  float s = 0.f;
  for (int v = 0; v < kV; v++) s += ivt[((long)b * kV + v) * kD + d];
  mv[i] = s * (1.f / kV);
}

__global__ __launch_bounds__(64) void cam2d_k(const float* __restrict__ mv,
                                              const float* __restrict__ w2,
                                              const float* __restrict__ b2,
                                              float* __restrict__ o)
{
  int bc = blockIdx.x;
  int b = bc / kC, c = bc - b * kC;
  float s = 0.f;
  for (int d = threadIdx.x; d < kD; d += 64) s += mv[b * kD + d] * w2[d * kC + c];
  for (int w = 32; w > 0; w >>= 1) s += __shfl_down(s, w);
  if (threadIdx.x == 0) o[bc] = s + b2[c];
}

__global__ void fin_k(const float* __restrict__ cl, const float* __restrict__ ts,
                      float* __restrict__ outp)
{
  outp[400] = cl[0] * (1.f / ((float)kB * (float)kN * (float)kD));
  outp[401] = ts[0] * (1.f / (kDepth * kB));
}

// ---------------- host-side dispatch helpers -------------------------------
static void gemm_disp(hipStream_t st, const float* A, const float* Bm, const float* bias,
                      const float* Res, float* C, int M, int N, int K,
                      int lda, int ldb, int ldc,
                      long sAb, long sAh, long sBb, long sBh, long sCb, long sCh,
                      int Z, int Hdim, float alpha, int act, bool trb, bool prelu)
{
  dim3 blk(256, 1, 1);
  long bigBlocks = (long)((M + 127) / 128) * ((N + 127) / 128) * Z;
  // big path only when it alone can fill the GPU (>=1.5 blocks/CU);
  // otherwise the 64x64 path gives 4x the block count for latency hiding.
  bool big = (N >= 96) && (bigBlocks >= 384);
#define GARGS A, Bm, bias, Res, C, M, N, K, lda, ldb, ldc, sAb, sAh, sBb, sBh, sCb, sCh, Hdim, alpha
  if (big) {
    dim3 g((N + 127) / 128, (M + 127) / 128, Z);
    if (prelu)          gemm_k<128, 128, 8, 8, 0, false, true ><<<g, blk, 0, st>>>(GARGS);
    else if (trb)       gemm_k<128, 128, 8, 8, 0, true,  false><<<g, blk, 0, st>>>(GARGS);
    else if (act == 1)  gemm_k<128, 128, 8, 8, 1, false, false><<<g, blk, 0, st>>>(GARGS);
    else if (act == 2)  gemm_k<128, 128, 8, 8, 2, false, false><<<g, blk, 0, st>>>(GARGS);
    else                gemm_k<128, 128, 8, 8, 0, false, false><<<g, blk, 0, st>>>(GARGS);
  } else {
    dim3 g((N + 63) / 64, (M + 63) / 64, Z);
    if (prelu)          gemm_k<64, 64, 4, 4, 0, false, true ><<<g, blk, 0, st>>>(GARGS);
    else if (trb)       gemm_k<64, 64, 4, 4, 0, true,  false><<<g, blk, 0, st>>>(GARGS);
    else if (act == 1)  gemm_k<64, 64, 4, 4, 1, false, false><<<g, blk, 0, st>>>(GARGS);
    else if (act == 2)  gemm_k<64, 64, 4, 4, 2, false, false><<<g, blk, 0, st>>>(GARGS);
    else                gemm_k<64, 64, 4, 4, 0, false, false><<<g, blk, 0, st>>>(GARGS);
  }
#undef GARGS
}

static void linear(hipStream_t st, const float* A, const float* W, const float* bias,
                   const float* Res, float* C, int M, int N, int K, int act)
{
  gemm_disp(st, A, W, bias, Res, C, M, N, K, K, N, N, 0, 0, 0, 0, 0, 0, 1, 1, 1.f, act, false, false);
}

// materialized MHA: P = softmax(scale * Q K^T); O = P V
// qb: (B,Tq,ldq) head-major cols; kb/vb: (B,Tk,ldkv) head-major cols
static void attention(hipStream_t st, const float* qb, int ldq, const float* kb,
                      const float* vb, int ldkv, int Tq, int Tk, float* P, float* O)
{
  gemm_disp(st, qb, kb, nullptr, nullptr, P, Tq, Tk, kDH, ldq, ldkv, Tk,
            (long)Tq * ldq, kDH, (long)Tk * ldkv, kDH, (long)kH * Tq * Tk, (long)Tq * Tk,
            kB * kH, kH, kScale, 0, true, false);
  softmax_k<<<dim3(kB * kH * Tq), dim3(256), 0, st>>>(P, Tk);
  gemm_disp(st, P, vb, nullptr, nullptr, O, Tq, kDH, Tk, Tk, ldkv, kD,
            (long)kH * Tq * Tk, (long)Tq * Tk, (long)Tk * ldkv, kDH, (long)Tq * kD, kDH,
            kB * kH, kH, 1.f, 0, false, false);
}

}  // namespace

extern "C" void kernel_launch(void* const* d_in, const int* in_sizes, int n_in,
                              void* d_out, int out_size, void* d_ws, size_t ws_size,
                              hipStream_t stream)
{
  (void)in_sizes; (void)n_in; (void)out_size; (void)ws_size;
  const float* point_feat  = (const float*)d_in[0];
  const float* point_coord = (const float*)d_in[1];
  const float* ivt         = (const float*)d_in[2];
  const int*   sv          = (const int*)d_in[3];
  const float* cls_token   = (const float*)d_in[4];
  const float* cls_pos     = (const float*)d_in[5];
  const float* view_pos    = (const float*)d_in[6];
  const float* pos_w1 = (const float*)d_in[7];
  const float* pos_b1 = (const float*)d_in[8];
  const float* pos_w2 = (const float*)d_in[9];
  const float* pos_b2 = (const float*)d_in[10];
  const float* pos_w3 = (const float*)d_in[11];
  const float* pos_b3 = (const float*)d_in[12];
  const float* enc_qkv_w  = (const float*)d_in[13];
  const float* enc_qkv_b  = (const float*)d_in[14];
  const float* enc_proj_w = (const float*)d_in[15];
  const float* enc_proj_b = (const float*)d_in[16];
  const float* enc_ln1_g  = (const float*)d_in[17];
  const float* enc_ln1_b  = (const float*)d_in[18];
  const float* enc_ln2_g  = (const float*)d_in[19];
  const float* enc_ln2_b  = (const float*)d_in[20];
  const float* enc_mlp_w1 = (const float*)d_in[21];
  const float* enc_mlp_b1 = (const float*)d_in[22];
  const float* enc_mlp_w2 = (const float*)d_in[23];
  const float* enc_mlp_b2 = (const float*)d_in[24];
  const float* dec_q_w    = (const float*)d_in[25];
  const float* dec_q_b    = (const float*)d_in[26];
  const float* dec_kv_w   = (const float*)d_in[27];
  const float* dec_kv_b   = (const float*)d_in[28];
  const float* dec_proj_w = (const float*)d_in[29];
  const float* dec_proj_b = (const float*)d_in[30];
  const float* dec_lnq_g  = (const float*)d_in[31];
  const float* dec_lnq_b  = (const float*)d_in[32];
  const float* dec_lnkv_g = (const float*)d_in[33];
  const float* dec_lnkv_b = (const float*)d_in[34];
  const float* dec_ln2_g  = (const float*)d_in[35];
  const float* dec_ln2_b  = (const float*)d_in[36];
  const float* dec_mlp_w1 = (const float*)d_in[37];
  const float* dec_mlp_b1 = (const float*)d_in[38];
  const float* dec_mlp_w2 = (const float*)d_in[39];
  const float* dec_mlp_b2 = (const float*)d_in[40];
  const float* head2d_w = (const float*)d_in[41];
  const float* head2d_b = (const float*)d_in[42];
  const float* head3d_w = (const float*)d_in[43];
  const float* head3d_b = (const float*)d_in[44];
  float* out = (float*)d_out;

  float* w = (float*)d_ws;
  size_t off = 0;
  auto alloc = [&](size_t n) { float* p = w + off; off += n; return p; };

  // region A: segment-sum partials (early) aliased with attention scores (late)
  const size_t scores_sz = (size_t)kB * kH * kTX * kTX;            // 17.4M floats
  const size_t probs_sz  = (size_t)kB * kH * kTV * kTX;            // 468K floats
  float* regionA  = alloc(scores_sz + 2 * probs_sz);
  float* seg_part = regionA;        // dead before encoders run
  float* scores   = regionA;
  float* probs1   = regionA + scores_sz;
  float* probs2   = probs1 + probs_sz;

  float* cpart    = alloc((size_t)kB * NSLICE * kS);
  float* counts   = alloc((size_t)kB * kS);
  float* pooled   = alloc((size_t)kB * kS * kD);
  float* csum     = alloc((size_t)kB * kS * 3);   // zero region start
  float* closs    = alloc(1);
  float* simacc   = alloc(1);
  float* pcoord   = alloc((size_t)kB * kS * 3);
  float* ph1      = alloc((size_t)kB * kS * kD);
  float* ph2      = alloc((size_t)kB * kS * kD);
  float* posb     = alloc((size_t)kB * kS * kD);
  float* x_view   = alloc((size_t)kB * kTV * kD);
  float* h_view   = alloc((size_t)kB * kTV * kD);
  float* qkv_view = alloc((size_t)kB * kTV * 3 * kD);
  float* o_view   = alloc((size_t)kB * kTV * kD);
  float* mlp_view = alloc((size_t)kB * kTV * kMH);
  float* x_vox    = alloc((size_t)kB * kTX * kD);
  float* h_vox    = alloc((size_t)kB * kTX * kD);
  float* qkv_vox  = alloc((size_t)kB * kTX * 3 * kD);
  float* o_vox    = alloc((size_t)kB * kTX * kD);
  float* mlp_vox  = alloc((size_t)kB * kTX * kMH);
  float* q_small  = alloc((size_t)kB * kTV * kD);
  float* kv_big   = alloc((size_t)kB * kTX * 2 * kD);
  float* q_big    = alloc((size_t)kB * kTX * kD);
  float* kv_small = alloc((size_t)kB * kTV * 2 * kD);
  float* meanv    = alloc((size_t)kB * kD);

  // zero the atomic accumulators (ws is poisoned 0xAA before each call)
  hipMemsetAsync(csum, 0, ((size_t)kB * kS * 3 + 2) * sizeof(float), stream);

  // ---- point-cloud pooling + consistency loss ----
  segsum_k<<<dim3(DCH, NSLICE, kB), 256, 0, stream>>>(point_feat, sv, seg_part);
  segcnt_k<<<dim3(NSLICE, kB), 256, 0, stream>>>(sv, cpart);
  cntfin_k<<<dim3((kB * kS + 255) / 256), 256, 0, stream>>>(cpart, counts);
  poolfin_k<<<dim3((kB * kS * kD + 255) / 256), 256, 0, stream>>>(seg_part, counts, pooled);
  coordsum_k<<<dim3((kB * kN + 255) / 256), 256, 0, stream>>>(point_coord, sv, csum);
  coordfin_k<<<dim3((kB * kS * 3 + 255) / 256), 256, 0, stream>>>(csum, counts, pcoord);
  closs_k<<<dim3(2048), 256, 0, stream>>>(point_feat, sv, pooled, closs);

  // ---- position MLP ----
  linear(stream, pcoord, pos_w1, pos_b1, nullptr, ph1, kB * kS, kD, 3, 1);
  linear(stream, ph1, pos_w2, pos_b2, nullptr, ph2, kB * kS, kD, kD, 1);
  linear(stream, ph2, pos_w3, pos_b3, nullptr, posb, kB * kS, kD, kD, 0);

  // ---- build token streams ----
  build_k<<<dim3(((unsigned)(kB * kTV * kD) + 255) / 256), 256, 0, stream>>>(
      cls_token, cls_pos, ivt, view_pos, x_view, kTV, kV, 0);
  build_k<<<dim3(((unsigned)(kB * kTX * kD) + 255) / 256), 256, 0, stream>>>(
      cls_token, cls_pos, pooled, posb, x_vox, kTX, kS, 1);

  // ---- encoders (e=0 view, e=1 vox) ----
  auto encoder = [&](float* x, int T, int e, float* h, float* qkv, float* o, float* mlp) {
    int M = kB * T;
    for (int dl = 0; dl < kDepth; dl++) {
      int wi = e * kDepth + dl;
      ln_k<<<dim3(M), 256, 0, stream>>>(x, enc_ln1_g + wi * kD, enc_ln1_b + wi * kD, h, M);
      linear(stream, h, enc_qkv_w + (long)wi * kD * 3 * kD, enc_qkv_b + (long)wi * 3 * kD,
             nullptr, qkv, M, 3 * kD, kD, 0);
      attention(stream, qkv, 3 * kD, qkv + kD, qkv + 2 * kD, 3 * kD, T, T, scores, o);
      linear(stream, o, enc_proj_w + (long)wi * kD * kD, enc_proj_b + (long)wi * kD, x, x, M, kD, kD, 0);
      ln_k<<<dim3(M), 256, 0, stream>>>(x, enc_ln2_g + wi * kD, enc_ln2_b + wi * kD, h, M);
      linear(stream, h, enc_mlp_w1 + (long)wi * kD * kMH, enc_mlp_b1 + (long)wi * kMH,
             nullptr, mlp, M, kMH, kD, 2);
      linear(stream, mlp, enc_mlp_w2 + (long)wi * kMH * kD, enc_mlp_b2 + (long)wi * kD, x, x, M, kD, kMH, 0);
    }
  };
  encoder(x_view, kTV, 0, h_view, qkv_view, o_view, mlp_view);
  meanD_k<<<dim3(kB * kC), 64, 0, stream>>>(x_view, out + 80, kTV);   // mct_logits_2d

  encoder(x_vox, kTX, 1, h_vox, qkv_vox, o_vox, mlp_vox);
  meanD_k<<<dim3(kB * kC), 64, 0, stream>>>(x_vox, out + 160, kTX);   // mct_logits_3d

  // voxel_cam = relu(vox_enc[:, C:]) @ head3d_w + b   (pre-decoder!)
  gemm_disp(stream, x_vox + (long)kC * kD, head3d_w, head3d_b, nullptr, out + 402,
            kS, kC, kD, kD, kC, kC,
            (long)kTX * kD, 0, 0, 0, (long)kS * kC, 0,
            kB, 1, 1.f, 0, false, true);
  cam3d_k<<<dim3(kB * kC), 256, 0, stream>>>(out + 402, out + 320);   // cam_logits_3d
  meanv_k<<<dim3((kB * kD + 255) / 256), 256, 0, stream>>>(ivt, meanv);
  cam2d_k<<<dim3(kB * kC), 64, 0, stream>>>(meanv, head2d_w, head2d_b, out + 240);  // cam_logits_2d

  // ---- cross decoder ----
  for (int dl = 0; dl < kDepth; dl++) {
    int w0 = dl, w1 = kDepth + dl;  // (branch, layer) flat index
    ln_k<<<dim3(kB * kTV), 256, 0, stream>>>(x_view, dec_lnq_g + w0 * kD, dec_lnq_b + w0 * kD, h_view, kB * kTV);
    ln_k<<<dim3(kB * kTX), 256, 0, stream>>>(x_vox, dec_lnkv_g + w0 * kD, dec_lnkv_b + w0 * kD, h_vox, kB * kTX);
    linear(stream, h_view, dec_q_w + (long)w0 * kD * kD, dec_q_b + (long)w0 * kD, nullptr, q_small, kB * kTV, kD, kD, 0);
    linear(stream, h_vox, dec_kv_w + (long)w0 * kD * 2 * kD, dec_kv_b + (long)w0 * 2 * kD, nullptr, kv_big, kB * kTX, 2 * kD, kD, 0);
    attention(stream, q_small, kD, kv_big, kv_big + kD, 2 * kD, kTV, kTX, probs1, o_view);
    simloss_k<<<dim3(kB), 64, 0, stream>>>(probs1, simacc);

    ln_k<<<dim3(kB * kTX), 256, 0, stream>>>(x_vox, dec_lnq_g + w1 * kD, dec_lnq_b + w1 * kD, h_vox, kB * kTX);
    ln_k<<<dim3(kB * kTV), 256, 0, stream>>>(x_view, dec_lnkv_g + w1 * kD, dec_lnkv_b + w1 * kD, h_view, kB * kTV);
    linear(stream, h_vox, dec_q_w + (long)w1 * kD * kD, dec_q_b + (long)w1 * kD, nullptr, q_big, kB * kTX, kD, kD, 0);
    linear(stream, h_view, dec_kv_w + (long)w1 * kD * 2 * kD, dec_kv_b + (long)w1 * 2 * kD, nullptr, kv_small, kB * kTV, 2 * kD, kD, 0);
    attention(stream, q_big, kD, kv_small, kv_small + kD, 2 * kD, kTX, kTV, probs2, o_vox);

    linear(stream, o_view, dec_proj_w + (long)w0 * kD * kD, dec_proj_b + (long)w0 * kD, x_view, x_view, kB * kTV, kD, kD, 0);
    linear(stream, o_vox, dec_proj_w + (long)w1 * kD * kD, dec_proj_b + (long)w1 * kD, x_vox, x_vox, kB * kTX, kD, kD, 0);

    ln_k<<<dim3(kB * kTV), 256, 0, stream>>>(x_view, dec_ln2_g + w0 * kD, dec_ln2_b + w0 * kD, h_view, kB * kTV);
    linear(stream, h_view, dec_mlp_w1 + (long)w0 * kD * kMH, dec_mlp_b1 + (long)w0 * kMH, nullptr, mlp_view, kB * kTV, kMH, kD, 2);
    linear(stream, mlp_view, dec_mlp_w2 + (long)w0 * kMH * kD, dec_mlp_b2 + (long)w0 * kD, x_view, x_view, kB * kTV, kD, kMH, 0);
    ln_k<<<dim3(kB * kTX), 256, 0, stream>>>(x_vox, dec_ln2_g + w1 * kD, dec_ln2_b + w1 * kD, h_vox, kB * kTX);
    linear(stream, h_vox, dec_mlp_w1 + (long)w1 * kD * kMH, dec_mlp_b1 + (long)w1 * kMH, nullptr, mlp_vox, kB * kTX, kMH, kD, 2);
    linear(stream, mlp_vox, dec_mlp_w2 + (long)w1 * kMH * kD, dec_mlp_b2 + (long)w1 * kD, x_vox, x_vox, kB * kTX, kD, kMH, 0);
  }

  cross_k<<<dim3(kB * kC), 64, 0, stream>>>(x_vox, x_view, out + 0);  // cross_mct_logits
  fin_k<<<dim3(1), 1, 0, stream>>>(closs, simacc, out);               // consistent + token_sim
}

// Round 4
// 9452.583 us; speedup vs baseline: 1.0872x; 1.0872x over previous
//
#include <hip/hip_runtime.h>

namespace {

constexpr int kB = 4, kN = 60000, kS = 1024, kV = 8, kD = 256, kH = 4, kDepth = 4, kC = 20;
constexpr int kDH = 64;           // D / H
constexpr int kMH = 1024;         // 4*D
constexpr int kTV = kC + kV;      // 28 view tokens
constexpr int kTX = kC + kS;      // 1044 vox tokens
constexpr float kScale = 0.125f;  // 1/sqrt(64)

constexpr int NSLICE = 8;         // slices over N for segment sum
constexpr int DC = 8;             // dims per segsum block (32B/point granule)
constexpr int DCH = kD / DC;      // 32 d-chunks
constexpr int SPAD = DC + 1;      // pad 9 -> (9*s+ld)%32 spreads atomic banks

// ---------------------------------------------------------------------------
// Generic tiled fp32 GEMM: C[M,N] = act(alpha * A@B + bias) + Res
//   batched over gridDim.z with separate (batch, head) strides.
//   TRB: B element (k,n) read as Bm[n*ldb + k]  (used for Q @ K^T)
//   PRELU: relu applied to A elements on load (used for relu(vox)@head3d_w)
// Microtile: 16x16 threads; thread (tx,ty) owns 4-consecutive cols at
//   {tx*4 + jb*64} and 4-consecutive rows at {ty*4 + ib*64} -> LDS fragment
//   reads are ds_read_b128 with broadcast across the other thread axis.
// ---------------------------------------------------------------------------
template <int BM, int BN, int TM, int TN, int ACT, bool TRB, bool PRELU>
__global__ __launch_bounds__(256) void gemm_k(
    const float* __restrict__ A, const float* __restrict__ Bm,
    const float* __restrict__ bias, const float* __restrict__ Res,
    float* __restrict__ C, int M, int N, int K, int lda, int ldb, int ldc,
    long sAb, long sAh, long sBb, long sBh, long sCb, long sCh, int Hdim, float alpha)
{
  constexpr int KT = 16;
  constexpr int MB = TM / 4;          // 4-row blocks per thread
  constexpr int NB = TN / 4;          // 4-col blocks per thread
  constexpr int AE = BM * KT / 256;
  constexpr int BE = BN * KT / 256;
  __shared__ float As[KT][BM + 4];    // +4 keeps rows 16B-aligned
  __shared__ float Bs[KT][BN + 4];
  const int z = blockIdx.z;
  const int bi = z / Hdim, hi = z - bi * Hdim;
  A += (long)bi * sAb + (long)hi * sAh;
  Bm += (long)bi * sBb + (long)hi * sBh;
  C += (long)bi * sCb + (long)hi * sCh;
  const float* R = Res;
  if (R) R += (long)bi * sCb + (long)hi * sCh;
  const int n0 = blockIdx.x * BN, m0 = blockIdx.y * BM;
  const int tid = threadIdx.x;
  const int tx = tid % 16, ty = tid / 16;
  float acc[TM][TN];
#pragma unroll
  for (int i = 0; i < TM; i++)
#pragma unroll
    for (int j = 0; j < TN; j++) acc[i][j] = 0.f;

  for (int k0 = 0; k0 < K; k0 += KT) {
#pragma unroll
    for (int i = 0; i < AE; i++) {
      int e = tid + i * 256;
      int row = e >> 4, kk = e & 15;
      int gm = m0 + row, gk = k0 + kk;
      float v = 0.f;
      if (gm < M && gk < K) v = A[(long)gm * lda + gk];
      if (PRELU) v = fmaxf(v, 0.f);
      As[kk][row] = v;
    }
#pragma unroll
    for (int i = 0; i < BE; i++) {
      int e = tid + i * 256;
      int kk, col;
      if (TRB) { kk = e & 15; col = e >> 4; }
      else     { col = e % BN; kk = e / BN; }
      int gk = k0 + kk, gn = n0 + col;
      float v = 0.f;
      if (gk < K && gn < N) v = TRB ? Bm[(long)gn * ldb + gk] : Bm[(long)gk * ldb + gn];
      Bs[kk][col] = v;
    }
    __syncthreads();
#pragma unroll
    for (int kk = 0; kk < KT; kk++) {
      const float4* Ar = reinterpret_cast<const float4*>(&As[kk][0]);
      const float4* Br = reinterpret_cast<const float4*>(&Bs[kk][0]);
      float4 af[MB], bf[NB];
#pragma unroll
      for (int ib = 0; ib < MB; ib++) af[ib] = Ar[ty + ib * 16];
#pragma unroll
      for (int jb = 0; jb < NB; jb++) bf[jb] = Br[tx + jb * 16];
      float av[TM], bv[TN];
#pragma unroll
      for (int ib = 0; ib < MB; ib++) {
        av[ib * 4 + 0] = af[ib].x; av[ib * 4 + 1] = af[ib].y;
        av[ib * 4 + 2] = af[ib].z; av[ib * 4 + 3] = af[ib].w;
      }
#pragma unroll
      for (int jb = 0; jb < NB; jb++) {
        bv[jb * 4 + 0] = bf[jb].x; bv[jb * 4 + 1] = bf[jb].y;
        bv[jb * 4 + 2] = bf[jb].z; bv[jb * 4 + 3] = bf[jb].w;
      }
#pragma unroll
      for (int i = 0; i < TM; i++)
#pragma unroll
        for (int j = 0; j < TN; j++) acc[i][j] += av[i] * bv[j];
    }
    __syncthreads();
  }
#pragma unroll
  for (int i = 0; i < TM; i++) {
    int gm = m0 + (i >> 2) * 64 + ty * 4 + (i & 3);
    if (gm >= M) continue;
#pragma unroll
    for (int j = 0; j < TN; j++) {
      int gn = n0 + (j >> 2) * 64 + tx * 4 + (j & 3);
      if (gn >= N) continue;
      float v = acc[i][j] * alpha;
      if (bias) v += bias[gn];
      if (ACT == 1) v = fmaxf(v, 0.f);
      else if (ACT == 2) {
        float u = v;
        float t = 0.7978845608028654f * (u + 0.044715f * u * u * u);
        v = u / (1.f + __expf(-2.f * t));   // 0.5u(1+tanh t), overflow-safe
      }
      if (R) v += R[(long)gm * ldc + gn];
      C[(long)gm * ldc + gn] = v;
    }
  }
}

// ---------------- LayerNorm over D=256, one block per row -----------------
__global__ __launch_bounds__(256) void ln_k(const float* __restrict__ x,
                                            const float* __restrict__ g,
                                            const float* __restrict__ b,
                                            float* __restrict__ o, int rows)
{
  __shared__ float red[256];
  __shared__ float stat;
  int row = blockIdx.x;
  int t = threadIdx.x;
  float v = x[(long)row * kD + t];
  red[t] = v;
  __syncthreads();
  for (int s = 128; s > 0; s >>= 1) { if (t < s) red[t] += red[t + s]; __syncthreads(); }
  if (t == 0) stat = red[0] * (1.f / kD);
  __syncthreads();
  float m = stat;
  float d = v - m;
  red[t] = d * d;
  __syncthreads();
  for (int s = 128; s > 0; s >>= 1) { if (t < s) red[t] += red[t + s]; __syncthreads(); }
  if (t == 0) stat = rsqrtf(red[0] * (1.f / kD) + 1e-5f);
  __syncthreads();
  o[(long)row * kD + t] = g[t] * d * stat + b[t];
}

// ---------------- row softmax (in place), one block per row ----------------
__global__ __launch_bounds__(256) void softmax_k(float* __restrict__ s, int L)
{
  long row = blockIdx.x;
  float* p = s + row * (long)L;
  int t = threadIdx.x;
  float rv[8];
  int nc = (L + 255) >> 8;
  float mx = -1e30f;
  for (int c = 0; c < nc; c++) {
    int i = t + c * 256;
    rv[c] = (i < L) ? p[i] : -1e30f;
    mx = fmaxf(mx, rv[c]);
  }
  __shared__ float red[256];
  __shared__ float bb;
  red[t] = mx; __syncthreads();
  for (int st = 128; st > 0; st >>= 1) { if (t < st) red[t] = fmaxf(red[t], red[t + st]); __syncthreads(); }
  if (t == 0) bb = red[0];
  __syncthreads();
  float bm = bb;
  float sum = 0.f;
  for (int c = 0; c < nc; c++) {
    int i = t + c * 256;
    if (i < L) { rv[c] = __expf(rv[c] - bm); sum += rv[c]; }
  }
  red[t] = sum; __syncthreads();
  for (int st = 128; st > 0; st >>= 1) { if (t < st) red[t] += red[t + st]; __syncthreads(); }
  if (t == 0) bb = 1.f / red[0];
  __syncthreads();
  float inv = bb;
  for (int c = 0; c < nc; c++) {
    int i = t + c * 256;
    if (i < L) p[i] = rv[c] * inv;
  }
}

// ---------------- segment sum of point_feat via LDS (36KB, 4 blk/CU) -------
__global__ __launch_bounds__(256) void segsum_k(const float* __restrict__ pf,
                                                const int* __restrict__ sv,
                                                float* __restrict__ part)
{
  __shared__ float acc[kS * SPAD];  // 36864 B -> 4 blocks/CU
  int t = threadIdx.x;
  for (int i = t; i < kS * SPAD; i += 256) acc[i] = 0.f;
  __syncthreads();
  int dc = blockIdx.x, sl = blockIdx.y, b = blockIdx.z;
  const int per = kN / NSLICE;
  int n0 = sl * per, n1 = n0 + per;
  int ld_ = t & (DC - 1), pg = t >> 3;   // 32 points in parallel per block
#pragma unroll 4
  for (int n = n0 + pg; n < n1; n += 32) {
    int s = sv[b * kN + n];
    float v = pf[((long)b * kN + n) * kD + dc * DC + ld_];
    atomicAdd(&acc[s * SPAD + ld_], v);
  }
  __syncthreads();
  float* outp = part + (((long)(b * NSLICE + sl) * DCH + dc) * (kS * DC));
  for (int i = t; i < kS * DC; i += 256) outp[i] = acc[(i >> 3) * SPAD + (i & 7)];
}

__global__ __launch_bounds__(256) void segcnt_k(const int* __restrict__ sv,
                                                float* __restrict__ cpart)
{
  __shared__ float cnt[kS];
  int t = threadIdx.x;
  for (int i = t; i < kS; i += 256) cnt[i] = 0.f;
  __syncthreads();
  int sl = blockIdx.x, b = blockIdx.y;
  const int per = kN / NSLICE;
  int n0 = sl * per, n1 = n0 + per;
  for (int n = n0 + t; n < n1; n += 256) atomicAdd(&cnt[sv[b * kN + n]], 1.f);
  __syncthreads();
  float* outp = cpart + (long)(b * NSLICE + sl) * kS;
  for (int i = t; i < kS; i += 256) outp[i] = cnt[i];
}

__global__ void cntfin_k(const float* __restrict__ cpart, float* __restrict__ counts)
{
  int i = blockIdx.x * 256 + threadIdx.x;
  if (i >= kB * kS) return;
  int b = i / kS, s = i - b * kS;
  float c = 0.f;
  for (int sl = 0; sl < NSLICE; sl++) c += cpart[(long)(b * NSLICE + sl) * kS + s];
  counts[i] = c;
}

__global__ void poolfin_k(const float* __restrict__ part, const float* __restrict__ counts,
                          float* __restrict__ pooled)
{
  long i = (long)blockIdx.x * 256 + threadIdx.x;
  if (i >= (long)kB * kS * kD) return;
  int d = (int)(i % kD);
  long bs = i / kD;
  int s = (int)(bs % kS), b = (int)(bs / kS);
  int dc = d / DC, dl = d - dc * DC;
  float sum = 0.f;
  for (int sl = 0; sl < NSLICE; sl++)
    sum += part[(((long)(b * NSLICE + sl) * DCH + dc) * (kS * DC)) + s * DC + dl];
  float c = counts[b * kS + s];
  pooled[i] = (c > 0.5f) ? sum / c : 0.f;
}

__global__ void coordsum_k(const float* __restrict__ pc, const int* __restrict__ sv,
                           float* __restrict__ csum)
{
  int i = blockIdx.x * 256 + threadIdx.x;
  if (i >= kB * kN) return;
  int b = i / kN;
  int s = sv[i];
  for (int j = 0; j < 3; j++)
    atomicAdd(&csum[((long)b * kS + s) * 3 + j], pc[(long)i * 3 + j]);
}

__global__ void coordfin_k(const float* __restrict__ csum, const float* __restrict__ counts,
                           float* __restrict__ pcoord)
{
  int i = blockIdx.x * 256 + threadIdx.x;
  if (i >= kB * kS * 3) return;
  int bs = i / 3;
  float c = counts[bs];
  pcoord[i] = (c > 0.5f) ? csum[i] / c : 0.f;
}

// ---------------- consistency loss: mean((pf - pooled[sv])^2) --------------
__global__ __launch_bounds__(256) void closs_k(const float* __restrict__ pf,
                                               const int* __restrict__ sv,
                                               const float* __restrict__ pooled,
                                               float* __restrict__ outp)
{
  const long total = (long)kB * kN * (kD / 4);
  float a = 0.f;
  for (long i = (long)blockIdx.x * 256 + threadIdx.x; i < total; i += (long)gridDim.x * 256) {
    long pnt = i >> 6;
    int dc = (int)(i & 63);
    int b = (int)(pnt / kN);
    int s = sv[pnt];
    float4 v = ((const float4*)pf)[i];
    float4 m = ((const float4*)pooled)[((long)b * kS + s) * (kD / 4) + dc];
    float dx = v.x - m.x, dy = v.y - m.y, dz = v.z - m.z, dw = v.w - m.w;
    a += dx * dx + dy * dy + dz * dz + dw * dw;
  }
  __shared__ float red[256];
  red[threadIdx.x] = a; __syncthreads();
  for (int s = 128; s > 0; s >>= 1) { if (threadIdx.x < s) red[threadIdx.x] += red[threadIdx.x + s]; __syncthreads(); }
  if (threadIdx.x == 0) atomicAdd(outp, red[0]);
}

// ---------------- token build: cls+pos || tok+pos --------------------------
__global__ void build_k(const float* __restrict__ cls, const float* __restrict__ clspos,
                        const float* __restrict__ tok, const float* __restrict__ pos,
                        float* __restrict__ x, int T, int Tt, int posBatched)
{
  long i = (long)blockIdx.x * 256 + threadIdx.x;
  long tot = (long)kB * T * kD;
  if (i >= tot) return;
  int d = (int)(i % kD);
  long bt = i / kD;
  int t = (int)(bt % T), b = (int)(bt / T);
  float v;
  if (t < kC) v = cls[t * kD + d] + clspos[t * kD + d];
  else {
    int tt = t - kC;
    v = tok[((long)b * Tt + tt) * kD + d] +
        pos[((long)(posBatched ? b * Tt : 0) + tt) * kD + d];
  }
  x[i] = v;
}

// ---------------- token-sim loss from MHA1 probs (B,H,28,1044) -------------
__global__ __launch_bounds__(64) void simloss_k(const float* __restrict__ probs,
                                                float* __restrict__ accum)
{
  int b = blockIdx.x;
  __shared__ float sim[kC][kC];
  int t = threadIdx.x;
  for (int e = t; e < kC * kC; e += 64) {
    int i = e / kC, j = e - i * kC;
    float s = 0.f;
    for (int h = 0; h < kH; h++)
      s += probs[(((long)(b * kH + h)) * kTV + i) * kTX + j];
    sim[i][j] = s * (1.f / kH);
  }
  __syncthreads();
  float local = 0.f;
  if (t < kC) {
    int i = t;
    float mx = -1e30f;
    for (int j = 0; j < kC; j++) mx = fmaxf(mx, sim[i][j]);
    float se = 0.f;
    for (int j = 0; j < kC; j++) se += expf(sim[i][j] - mx);
    float dr = sim[i][i] - mx - logf(se);
    float mc = -1e30f;
    for (int j = 0; j < kC; j++) mc = fmaxf(mc, sim[j][i]);
    float sc = 0.f;
    for (int j = 0; j < kC; j++) sc += expf(sim[j][i] - mc);
    float dcl = sim[i][i] - mc - logf(sc);
    local = dr + dcl;
  }
  for (int o = 32; o > 0; o >>= 1) local += __shfl_down(local, o);
  if (t == 0) atomicAdd(accum, local * (-0.5f / kC));
}

// ---------------- small output kernels -------------------------------------
__global__ __launch_bounds__(64) void meanD_k(const float* __restrict__ x,
                                              float* __restrict__ o, int T)
{
  int bc = blockIdx.x;
  int b = bc / kC, c = bc - b * kC;
  const float* r = x + ((long)b * T + c) * kD;
  float s = 0.f;
  for (int d = threadIdx.x; d < kD; d += 64) s += r[d];
  for (int w = 32; w > 0; w >>= 1) s += __shfl_down(s, w);
  if (threadIdx.x == 0) o[bc] = s * (1.f / kD);
}

__global__ __launch_bounds__(64) void cross_k(const float* __restrict__ xv,
                                              const float* __restrict__ xw,
                                              float* __restrict__ o)
{
  int bc = blockIdx.x;
  int b = bc / kC, c = bc - b * kC;
  const float* rv = xv + ((long)b * kTX + c) * kD;
  const float* rw = xw + ((long)b * kTV + c) * kD;
  float s = 0.f;
  for (int d = threadIdx.x; d < kD; d += 64) s += 0.5f * (rv[d] + rw[d]);
  for (int w = 32; w > 0; w >>= 1) s += __shfl_down(s, w);
  if (threadIdx.x == 0) o[bc] = s * (1.f / kD);
}

__global__ __launch_bounds__(256) void cam3d_k(const float* __restrict__ vc,
                                               float* __restrict__ o)
{
  __shared__ float red[256];
  int bc = blockIdx.x;
  int b = bc / kC, c = bc - b * kC;
  float s = 0.f;
  for (int t = threadIdx.x; t < kS; t += 256) s += vc[((long)b * kS + t) * kC + c];
  red[threadIdx.x] = s; __syncthreads();
  for (int st = 128; st > 0; st >>= 1) { if (threadIdx.x < st) red[threadIdx.x] += red[threadIdx.x + st]; __syncthreads(); }
  if (threadIdx.x == 0) o[bc] = red[0] * (1.f / kS);
}

__global__ void meanv_k(const float* __restrict__ ivt, float* __restrict__ mv)
{
  int i = blockIdx.x * 256 + threadIdx.x;
  if (i >= kB * kD) return;
  int b = i / kD, d = i - b * kD;
  float s = 0.f;
  for (int v = 0; v < kV; v++) s += ivt[((long)b * kV + v) * kD + d];
  mv[i] = s * (1.f / kV);
}

__global__ __launch_bounds__(64) void cam2d_k(const float* __restrict__ mv,
                                              const float* __restrict__ w2,
                                              const float* __restrict__ b2,
                                              float* __restrict__ o)
{
  int bc = blockIdx.x;
  int b = bc / kC, c = bc - b * kC;
  float s = 0.f;
  for (int d = threadIdx.x; d < kD; d += 64) s += mv[b * kD + d] * w2[d * kC + c];
  for (int w = 32; w > 0; w >>= 1) s += __shfl_down(s, w);
  if (threadIdx.x == 0) o[bc] = s + b2[c];
}

__global__ void fin_k(const float* __restrict__ cl, const float* __restrict__ ts,
                      float* __restrict__ outp)
{
  outp[400] = cl[0] * (1.f / ((float)kB * (float)kN * (float)kD));
  outp[401] = ts[0] * (1.f / (kDepth * kB));
}

// ---------------- host-side dispatch helpers -------------------------------
static void gemm_disp(hipStream_t st, const float* A, const float* Bm, const float* bias,
                      const float* Res, float* C, int M, int N, int K,
                      int lda, int ldb, int ldc,
                      long sAb, long sAh, long sBb, long sBh, long sCb, long sCh,
                      int Z, int Hdim, float alpha, int act, bool trb, bool prelu)
{
  dim3 blk(256, 1, 1);
  long bigBlocks = (long)((M + 127) / 128) * ((N + 127) / 128) * Z;
  // big path only when it alone can fill the GPU; else 64x64 gives 4x blocks.
  bool big = (N >= 96) && (bigBlocks >= 384);
#define GARGS A, Bm, bias, Res, C, M, N, K, lda, ldb, ldc, sAb, sAh, sBb, sBh, sCb, sCh, Hdim, alpha
  if (big) {
    dim3 g((N + 127) / 128, (M + 127) / 128, Z);
    if (prelu)          gemm_k<128, 128, 8, 8, 0, false, true ><<<g, blk, 0, st>>>(GARGS);
    else if (trb)       gemm_k<128, 128, 8, 8, 0, true,  false><<<g, blk, 0, st>>>(GARGS);
    else if (act == 1)  gemm_k<128, 128, 8, 8, 1, false, false><<<g, blk, 0, st>>>(GARGS);
    else if (act == 2)  gemm_k<128, 128, 8, 8, 2, false, false><<<g, blk, 0, st>>>(GARGS);
    else                gemm_k<128, 128, 8, 8, 0, false, false><<<g, blk, 0, st>>>(GARGS);
  } else {
    dim3 g((N + 63) / 64, (M + 63) / 64, Z);
    if (prelu)          gemm_k<64, 64, 4, 4, 0, false, true ><<<g, blk, 0, st>>>(GARGS);
    else if (trb)       gemm_k<64, 64, 4, 4, 0, true,  false><<<g, blk, 0, st>>>(GARGS);
    else if (act == 1)  gemm_k<64, 64, 4, 4, 1, false, false><<<g, blk, 0, st>>>(GARGS);
    else if (act == 2)  gemm_k<64, 64, 4, 4, 2, false, false><<<g, blk, 0, st>>>(GARGS);
    else                gemm_k<64, 64, 4, 4, 0, false, false><<<g, blk, 0, st>>>(GARGS);
  }
#undef GARGS
}

static void linear(hipStream_t st, const float* A, const float* W, const float* bias,
                   const float* Res, float* C, int M, int N, int K, int act)
{
  gemm_disp(st, A, W, bias, Res, C, M, N, K, K, N, N, 0, 0, 0, 0, 0, 0, 1, 1, 1.f, act, false, false);
}

// materialized MHA: P = softmax(scale * Q K^T); O = P V
// qb: (B,Tq,ldq) head-major cols; kb/vb: (B,Tk,ldkv) head-major cols
static void attention(hipStream_t st, const float* qb, int ldq, const float* kb,
                      const float* vb, int ldkv, int Tq, int Tk, float* P, float* O)
{
  gemm_disp(st, qb, kb, nullptr, nullptr, P, Tq, Tk, kDH, ldq, ldkv, Tk,
            (long)Tq * ldq, kDH, (long)Tk * ldkv, kDH, (long)kH * Tq * Tk, (long)Tq * Tk,
            kB * kH, kH, kScale, 0, true, false);
  softmax_k<<<dim3(kB * kH * Tq), dim3(256), 0, st>>>(P, Tk);
  gemm_disp(st, P, vb, nullptr, nullptr, O, Tq, kDH, Tk, Tk, ldkv, kD,
            (long)kH * Tq * Tk, (long)Tq * Tk, (long)Tk * ldkv, kDH, (long)Tq * kD, kDH,
            kB * kH, kH, 1.f, 0, false, false);
}

}  // namespace

extern "C" void kernel_launch(void* const* d_in, const int* in_sizes, int n_in,
                              void* d_out, int out_size, void* d_ws, size_t ws_size,
                              hipStream_t stream)
{
  (void)in_sizes; (void)n_in; (void)out_size; (void)ws_size;
  const float* point_feat  = (const float*)d_in[0];
  const float* point_coord = (const float*)d_in[1];
  const float* ivt         = (const float*)d_in[2];
  const int*   sv          = (const int*)d_in[3];
  const float* cls_token   = (const float*)d_in[4];
  const float* cls_pos     = (const float*)d_in[5];
  const float* view_pos    = (const float*)d_in[6];
  const float* pos_w1 = (const float*)d_in[7];
  const float* pos_b1 = (const float*)d_in[8];
  const float* pos_w2 = (const float*)d_in[9];
  const float* pos_b2 = (const float*)d_in[10];
  const float* pos_w3 = (const float*)d_in[11];
  const float* pos_b3 = (const float*)d_in[12];
  const float* enc_qkv_w  = (const float*)d_in[13];
  const float* enc_qkv_b  = (const float*)d_in[14];
  const float* enc_proj_w = (const float*)d_in[15];
  const float* enc_proj_b = (const float*)d_in[16];
  const float* enc_ln1_g  = (const float*)d_in[17];
  const float* enc_ln1_b  = (const float*)d_in[18];
  const float* enc_ln2_g  = (const float*)d_in[19];
  const float* enc_ln2_b  = (const float*)d_in[20];
  const float* enc_mlp_w1 = (const float*)d_in[21];
  const float* enc_mlp_b1 = (const float*)d_in[22];
  const float* enc_mlp_w2 = (const float*)d_in[23];
  const float* enc_mlp_b2 = (const float*)d_in[24];
  const float* dec_q_w    = (const float*)d_in[25];
  const float* dec_q_b    = (const float*)d_in[26];
  const float* dec_kv_w   = (const float*)d_in[27];
  const float* dec_kv_b   = (const float*)d_in[28];
  const float* dec_proj_w = (const float*)d_in[29];
  const float* dec_proj_b = (const float*)d_in[30];
  const float* dec_lnq_g  = (const float*)d_in[31];
  const float* dec_lnq_b  = (const float*)d_in[32];
  const float* dec_lnkv_g = (const float*)d_in[33];
  const float* dec_lnkv_b = (const float*)d_in[34];
  const float* dec_ln2_g  = (const float*)d_in[35];
  const float* dec_ln2_b  = (const float*)d_in[36];
  const float* dec_mlp_w1 = (const float*)d_in[37];
  const float* dec_mlp_b1 = (const float*)d_in[38];
  const float* dec_mlp_w2 = (const float*)d_in[39];
  const float* dec_mlp_b2 = (const float*)d_in[40];
  const float* head2d_w = (const float*)d_in[41];
  const float* head2d_b = (const float*)d_in[42];
  const float* head3d_w = (const float*)d_in[43];
  const float* head3d_b = (const float*)d_in[44];
  float* out = (float*)d_out;

  float* w = (float*)d_ws;
  size_t off = 0;
  auto alloc = [&](size_t n) { float* p = w + off; off += n; return p; };

  // region A: segment-sum partials (early) aliased with attention scores (late)
  const size_t scores_sz = (size_t)kB * kH * kTX * kTX;            // 17.4M floats
  const size_t probs_sz  = (size_t)kB * kH * kTV * kTX;            // 468K floats
  float* regionA  = alloc(scores_sz + 2 * probs_sz);
  float* seg_part = regionA;        // dead before encoders run
  float* scores   = regionA;
  float* probs1   = regionA + scores_sz;
  float* probs2   = probs1 + probs_sz;

  float* cpart    = alloc((size_t)kB * NSLICE * kS);
  float* counts   = alloc((size_t)kB * kS);
  float* pooled   = alloc((size_t)kB * kS * kD);
  float* csum     = alloc((size_t)kB * kS * 3);   // zero region start
  float* closs    = alloc(1);
  float* simacc   = alloc(1);
  float* pcoord   = alloc((size_t)kB * kS * 3);
  float* ph1      = alloc((size_t)kB * kS * kD);
  float* ph2      = alloc((size_t)kB * kS * kD);
  float* posb     = alloc((size_t)kB * kS * kD);
  float* x_view   = alloc((size_t)kB * kTV * kD);
  float* h_view   = alloc((size_t)kB * kTV * kD);
  float* qkv_view = alloc((size_t)kB * kTV * 3 * kD);
  float* o_view   = alloc((size_t)kB * kTV * kD);
  float* mlp_view = alloc((size_t)kB * kTV * kMH);
  float* x_vox    = alloc((size_t)kB * kTX * kD);
  float* h_vox    = alloc((size_t)kB * kTX * kD);
  float* qkv_vox  = alloc((size_t)kB * kTX * 3 * kD);
  float* o_vox    = alloc((size_t)kB * kTX * kD);
  float* mlp_vox  = alloc((size_t)kB * kTX * kMH);
  float* q_small  = alloc((size_t)kB * kTV * kD);
  float* kv_big   = alloc((size_t)kB * kTX * 2 * kD);
  float* q_big    = alloc((size_t)kB * kTX * kD);
  float* kv_small = alloc((size_t)kB * kTV * 2 * kD);
  float* meanv    = alloc((size_t)kB * kD);

  // zero the atomic accumulators (ws is poisoned 0xAA before each call)
  hipMemsetAsync(csum, 0, ((size_t)kB * kS * 3 + 2) * sizeof(float), stream);

  // ---- point-cloud pooling + consistency loss ----
  segsum_k<<<dim3(DCH, NSLICE, kB), 256, 0, stream>>>(point_feat, sv, seg_part);
  segcnt_k<<<dim3(NSLICE, kB), 256, 0, stream>>>(sv, cpart);
  cntfin_k<<<dim3((kB * kS + 255) / 256), 256, 0, stream>>>(cpart, counts);
  poolfin_k<<<dim3((kB * kS * kD + 255) / 256), 256, 0, stream>>>(seg_part, counts, pooled);
  coordsum_k<<<dim3((kB * kN + 255) / 256), 256, 0, stream>>>(point_coord, sv, csum);
  coordfin_k<<<dim3((kB * kS * 3 + 255) / 256), 256, 0, stream>>>(csum, counts, pcoord);
  closs_k<<<dim3(2048), 256, 0, stream>>>(point_feat, sv, pooled, closs);

  // ---- position MLP ----
  linear(stream, pcoord, pos_w1, pos_b1, nullptr, ph1, kB * kS, kD, 3, 1);
  linear(stream, ph1, pos_w2, pos_b2, nullptr, ph2, kB * kS, kD, kD, 1);
  linear(stream, ph2, pos_w3, pos_b3, nullptr, posb, kB * kS, kD, kD, 0);

  // ---- build token streams ----
  build_k<<<dim3(((unsigned)(kB * kTV * kD) + 255) / 256), 256, 0, stream>>>(
      cls_token, cls_pos, ivt, view_pos, x_view, kTV, kV, 0);
  build_k<<<dim3(((unsigned)(kB * kTX * kD) + 255) / 256), 256, 0, stream>>>(
      cls_token, cls_pos, pooled, posb, x_vox, kTX, kS, 1);

  // ---- encoders (e=0 view, e=1 vox) ----
  auto encoder = [&](float* x, int T, int e, float* h, float* qkv, float* o, float* mlp) {
    int M = kB * T;
    for (int dl = 0; dl < kDepth; dl++) {
      int wi = e * kDepth + dl;
      ln_k<<<dim3(M), 256, 0, stream>>>(x, enc_ln1_g + wi * kD, enc_ln1_b + wi * kD, h, M);
      linear(stream, h, enc_qkv_w + (long)wi * kD * 3 * kD, enc_qkv_b + (long)wi * 3 * kD,
             nullptr, qkv, M, 3 * kD, kD, 0);
      attention(stream, qkv, 3 * kD, qkv + kD, qkv + 2 * kD, 3 * kD, T, T, scores, o);
      linear(stream, o, enc_proj_w + (long)wi * kD * kD, enc_proj_b + (long)wi * kD, x, x, M, kD, kD, 0);
      ln_k<<<dim3(M), 256, 0, stream>>>(x, enc_ln2_g + wi * kD, enc_ln2_b + wi * kD, h, M);
      linear(stream, h, enc_mlp_w1 + (long)wi * kD * kMH, enc_mlp_b1 + (long)wi * kMH,
             nullptr, mlp, M, kMH, kD, 2);
      linear(stream, mlp, enc_mlp_w2 + (long)wi * kMH * kD, enc_mlp_b2 + (long)wi * kD, x, x, M, kD, kMH, 0);
    }
  };
  encoder(x_view, kTV, 0, h_view, qkv_view, o_view, mlp_view);
  meanD_k<<<dim3(kB * kC), 64, 0, stream>>>(x_view, out + 80, kTV);   // mct_logits_2d

  encoder(x_vox, kTX, 1, h_vox, qkv_vox, o_vox, mlp_vox);
  meanD_k<<<dim3(kB * kC), 64, 0, stream>>>(x_vox, out + 160, kTX);   // mct_logits_3d

  // voxel_cam = relu(vox_enc[:, C:]) @ head3d_w + b   (pre-decoder!)
  gemm_disp(stream, x_vox + (long)kC * kD, head3d_w, head3d_b, nullptr, out + 402,
            kS, kC, kD, kD, kC, kC,
            (long)kTX * kD, 0, 0, 0, (long)kS * kC, 0,
            kB, 1, 1.f, 0, false, true);
  cam3d_k<<<dim3(kB * kC), 256, 0, stream>>>(out + 402, out + 320);   // cam_logits_3d
  meanv_k<<<dim3((kB * kD + 255) / 256), 256, 0, stream>>>(ivt, meanv);
  cam2d_k<<<dim3(kB * kC), 64, 0, stream>>>(meanv, head2d_w, head2d_b, out + 240);  // cam_logits_2d

  // ---- cross decoder ----
  for (int dl = 0; dl < kDepth; dl++) {
    int w0 = dl, w1 = kDepth + dl;  // (branch, layer) flat index
    ln_k<<<dim3(kB * kTV), 256, 0, stream>>>(x_view, dec_lnq_g + w0 * kD, dec_lnq_b + w0 * kD, h_view, kB * kTV);
    ln_k<<<dim3(kB * kTX), 256, 0, stream>>>(x_vox, dec_lnkv_g + w0 * kD, dec_lnkv_b + w0 * kD, h_vox, kB * kTX);
    linear(stream, h_view, dec_q_w + (long)w0 * kD * kD, dec_q_b + (long)w0 * kD, nullptr, q_small, kB * kTV, kD, kD, 0);
    linear(stream, h_vox, dec_kv_w + (long)w0 * kD * 2 * kD, dec_kv_b + (long)w0 * 2 * kD, nullptr, kv_big, kB * kTX, 2 * kD, kD, 0);
    attention(stream, q_small, kD, kv_big, kv_big + kD, 2 * kD, kTV, kTX, probs1, o_view);
    simloss_k<<<dim3(kB), 64, 0, stream>>>(probs1, simacc);

    ln_k<<<dim3(kB * kTX), 256, 0, stream>>>(x_vox, dec_lnq_g + w1 * kD, dec_lnq_b + w1 * kD, h_vox, kB * kTX);
    ln_k<<<dim3(kB * kTV), 256, 0, stream>>>(x_view, dec_lnkv_g + w1 * kD, dec_lnkv_b + w1 * kD, h_view, kB * kTV);
    linear(stream, h_vox, dec_q_w + (long)w1 * kD * kD, dec_q_b + (long)w1 * kD, nullptr, q_big, kB * kTX, kD, kD, 0);
    linear(stream, h_view, dec_kv_w + (long)w1 * kD * 2 * kD, dec_kv_b + (long)w1 * 2 * kD, nullptr, kv_small, kB * kTV, 2 * kD, kD, 0);
    attention(stream, q_big, kD, kv_small, kv_small + kD, 2 * kD, kTX, kTV, probs2, o_vox);

    linear(stream, o_view, dec_proj_w + (long)w0 * kD * kD, dec_proj_b + (long)w0 * kD, x_view, x_view, kB * kTV, kD, kD, 0);
    linear(stream, o_vox, dec_proj_w + (long)w1 * kD * kD, dec_proj_b + (long)w1 * kD, x_vox, x_vox, kB * kTX, kD, kD, 0);

    ln_k<<<dim3(kB * kTV), 256, 0, stream>>>(x_view, dec_ln2_g + w0 * kD, dec_ln2_b + w0 * kD, h_view, kB * kTV);
    linear(stream, h_view, dec_mlp_w1 + (long)w0 * kD * kMH, dec_mlp_b1 + (long)w0 * kMH, nullptr, mlp_view, kB * kTV, kMH, kD, 2);
    linear(stream, mlp_view, dec_mlp_w2 + (long)w0 * kMH * kD, dec_mlp_b2 + (long)w0 * kD, x_view, x_view, kB * kTV, kD, kMH, 0);
    ln_k<<<dim3(kB * kTX), 256, 0, stream>>>(x_vox, dec_ln2_g + w1 * kD, dec_ln2_b + w1 * kD, h_vox, kB * kTX);
    linear(stream, h_vox, dec_mlp_w1 + (long)w1 * kD * kMH, dec_mlp_b1 + (long)w1 * kMH, nullptr, mlp_vox, kB * kTX, kMH, kD, 2);
    linear(stream, mlp_vox, dec_mlp_w2 + (long)w1 * kMH * kD, dec_mlp_b2 + (long)w1 * kD, x_vox, x_vox, kB * kTX, kD, kMH, 0);
  }

  cross_k<<<dim3(kB * kC), 64, 0, stream>>>(x_vox, x_view, out + 0);  // cross_mct_logits
  fin_k<<<dim3(1), 1, 0, stream>>>(closs, simacc, out);               // consistent + token_sim
}

// Round 7
// 5314.927 us; speedup vs baseline: 1.9336x; 1.7785x over previous
//
#include <hip/hip_runtime.h>

namespace {

constexpr int kB = 4, kN = 60000, kS = 1024, kV = 8, kD = 256, kH = 4, kDepth = 4, kC = 20;
constexpr int kDH = 64;           // D / H
constexpr int kMH = 1024;         // 4*D
constexpr int kTV = kC + kV;      // 28 view tokens
constexpr int kTX = kC + kS;      // 1044 vox tokens
constexpr float kScale = 0.125f;  // 1/sqrt(64)

constexpr int NSLICE = 8;         // slices over N for segment sum
constexpr int DC = 16;            // dims per segsum block (64B/point granule, 1x fetch)
constexpr int DCH = kD / DC;      // 16 d-chunks

// ---------------------------------------------------------------------------
// Generic tiled fp32 GEMM: C[M,N] = act(alpha * A@B + bias) + Res
//   batched over gridDim.z with separate (batch, head) strides.
//   TRB: B element (k,n) read as Bm[n*ldb + k]  (used for Q @ K^T)
//   PRELU: relu applied to A elements on load (used for relu(vox)@head3d_w)
// Register double-buffered staging: tile k+1's global loads issue right after
//   the barrier, so their latency hides under tile k's FMA block (the old
//   load->ds_write->barrier path exposed ~300-900 cyc per K-step).
// Microtile: 16x16 threads; thread (tx,ty) owns 4-consecutive cols at
//   {tx*4 + jb*64} and rows {ty*4 + ib*64} -> ds_read_b128 fragments.
// ---------------------------------------------------------------------------
template <int BM, int BN, int TM, int TN, int ACT, bool TRB, bool PRELU>
__global__ __launch_bounds__(256) void gemm_k(
    const float* __restrict__ A, const float* __restrict__ Bm,
    const float* __restrict__ bias, const float* __restrict__ Res,
    float* __restrict__ C, int M, int N, int K, int lda, int ldb, int ldc,
    long sAb, long sAh, long sBb, long sBh, long sCb, long sCh, int Hdim, float alpha)
{
  constexpr int KT = 16;
  constexpr int MB = TM / 4;          // 4-row blocks per thread
  constexpr int NB = TN / 4;          // 4-col blocks per thread
  constexpr int AE = BM * KT / 256;
  constexpr int BE = BN * KT / 256;
  __shared__ float As[KT][BM + 4];    // +4 keeps rows 16B-aligned
  __shared__ float Bs[KT][BN + 4];
  const int z = blockIdx.z;
  const int bi = z / Hdim, hi = z - bi * Hdim;
  A += (long)bi * sAb + (long)hi * sAh;
  Bm += (long)bi * sBb + (long)hi * sBh;
  C += (long)bi * sCb + (long)hi * sCh;
  const float* R = Res;
  if (R) R += (long)bi * sCb + (long)hi * sCh;
  const int n0 = blockIdx.x * BN, m0 = blockIdx.y * BM;
  const int tid = threadIdx.x;
  const int tx = tid % 16, ty = tid / 16;
  float acc[TM][TN];
#pragma unroll
  for (int i = 0; i < TM; i++)
#pragma unroll
    for (int j = 0; j < TN; j++) acc[i][j] = 0.f;

  float ra[AE], rb[BE];
  // prologue: load tile k0=0 into registers
#pragma unroll
  for (int i = 0; i < AE; i++) {
    int e = tid + i * 256;
    int row = e >> 4, kk = e & 15;
    int gm = m0 + row, gk = kk;
    float v = 0.f;
    if (gm < M && gk < K) v = A[(long)gm * lda + gk];
    if (PRELU) v = fmaxf(v, 0.f);
    ra[i] = v;
  }
#pragma unroll
  for (int i = 0; i < BE; i++) {
    int e = tid + i * 256;
    int kk, col;
    if (TRB) { kk = e & 15; col = e >> 4; }
    else     { col = e % BN; kk = e / BN; }
    int gk = kk, gn = n0 + col;
    float v = 0.f;
    if (gk < K && gn < N) v = TRB ? Bm[(long)gn * ldb + gk] : Bm[(long)gk * ldb + gn];
    rb[i] = v;
  }

  for (int k0 = 0; k0 < K; k0 += KT) {
    // commit the prefetched tile to LDS
#pragma unroll
    for (int i = 0; i < AE; i++) {
      int e = tid + i * 256;
      As[e & 15][e >> 4] = ra[i];
    }
#pragma unroll
    for (int i = 0; i < BE; i++) {
      int e = tid + i * 256;
      int kk, col;
      if (TRB) { kk = e & 15; col = e >> 4; }
      else     { col = e % BN; kk = e / BN; }
      Bs[kk][col] = rb[i];
    }
    __syncthreads();
    // issue next tile's global loads NOW -> latency hides under the FMA block
    if (k0 + KT < K) {
      const int kn = k0 + KT;
#pragma unroll
      for (int i = 0; i < AE; i++) {
        int e = tid + i * 256;
        int row = e >> 4, kk = e & 15;
        int gm = m0 + row, gk = kn + kk;
        float v = 0.f;
        if (gm < M && gk < K) v = A[(long)gm * lda + gk];
        if (PRELU) v = fmaxf(v, 0.f);
        ra[i] = v;
      }
#pragma unroll
      for (int i = 0; i < BE; i++) {
        int e = tid + i * 256;
        int kk, col;
        if (TRB) { kk = e & 15; col = e >> 4; }
        else     { col = e % BN; kk = e / BN; }
        int gk = kn + kk, gn = n0 + col;
        float v = 0.f;
        if (gk < K && gn < N) v = TRB ? Bm[(long)gn * ldb + gk] : Bm[(long)gk * ldb + gn];
        rb[i] = v;
      }
    }
#pragma unroll
    for (int kk = 0; kk < KT; kk++) {
      const float4* Ar = reinterpret_cast<const float4*>(&As[kk][0]);
      const float4* Br = reinterpret_cast<const float4*>(&Bs[kk][0]);
      float4 af[MB], bf[NB];
#pragma unroll
      for (int ib = 0; ib < MB; ib++) af[ib] = Ar[ty + ib * 16];
#pragma unroll
      for (int jb = 0; jb < NB; jb++) bf[jb] = Br[tx + jb * 16];
      float av[TM], bv[TN];
#pragma unroll
      for (int ib = 0; ib < MB; ib++) {
        av[ib * 4 + 0] = af[ib].x; av[ib * 4 + 1] = af[ib].y;
        av[ib * 4 + 2] = af[ib].z; av[ib * 4 + 3] = af[ib].w;
      }
#pragma unroll
      for (int jb = 0; jb < NB; jb++) {
        bv[jb * 4 + 0] = bf[jb].x; bv[jb * 4 + 1] = bf[jb].y;
        bv[jb * 4 + 2] = bf[jb].z; bv[jb * 4 + 3] = bf[jb].w;
      }
#pragma unroll
      for (int i = 0; i < TM; i++)
#pragma unroll
        for (int j = 0; j < TN; j++) acc[i][j] += av[i] * bv[j];
    }
    __syncthreads();
  }
#pragma unroll
  for (int i = 0; i < TM; i++) {
    int gm = m0 + (i >> 2) * 64 + ty * 4 + (i & 3);
    if (gm >= M) continue;
#pragma unroll
    for (int j = 0; j < TN; j++) {
      int gn = n0 + (j >> 2) * 64 + tx * 4 + (j & 3);
      if (gn >= N) continue;
      float v = acc[i][j] * alpha;
      if (bias) v += bias[gn];
      if (ACT == 1) v = fmaxf(v, 0.f);
      else if (ACT == 2) {
        float u = v;
        float t = 0.7978845608028654f * (u + 0.044715f * u * u * u);
        v = u / (1.f + __expf(-2.f * t));   // 0.5u(1+tanh t), overflow-safe
      }
      if (R) v += R[(long)gm * ldc + gn];
      C[(long)gm * ldc + gn] = v;
    }
  }
}

// ---------------- LayerNorm over D=256, one block per row -----------------
__global__ __launch_bounds__(256) void ln_k(const float* __restrict__ x,
                                            const float* __restrict__ g,
                                            const float* __restrict__ b,
                                            float* __restrict__ o, int rows)
{
  __shared__ float red[256];
  __shared__ float stat;
  int row = blockIdx.x;
  int t = threadIdx.x;
  float v = x[(long)row * kD + t];
  red[t] = v;
  __syncthreads();
  for (int s = 128; s > 0; s >>= 1) { if (t < s) red[t] += red[t + s]; __syncthreads(); }
  if (t == 0) stat = red[0] * (1.f / kD);
  __syncthreads();
  float m = stat;
  float d = v - m;
  red[t] = d * d;
  __syncthreads();
  for (int s = 128; s > 0; s >>= 1) { if (t < s) red[t] += red[t + s]; __syncthreads(); }
  if (t == 0) stat = rsqrtf(red[0] * (1.f / kD) + 1e-5f);
  __syncthreads();
  o[(long)row * kD + t] = g[t] * d * stat + b[t];
}

// ---------------- row softmax (in place), one block per row ----------------
__global__ __launch_bounds__(256) void softmax_k(float* __restrict__ s, int L)
{
  long row = blockIdx.x;
  float* p = s + row * (long)L;
  int t = threadIdx.x;
  float rv[8];
  int nc = (L + 255) >> 8;
  float mx = -1e30f;
  for (int c = 0; c < nc; c++) {
    int i = t + c * 256;
    rv[c] = (i < L) ? p[i] : -1e30f;
    mx = fmaxf(mx, rv[c]);
  }
  __shared__ float red[256];
  __shared__ float bb;
  red[t] = mx; __syncthreads();
  for (int st = 128; st > 0; st >>= 1) { if (t < st) red[t] = fmaxf(red[t], red[t + st]); __syncthreads(); }
  if (t == 0) bb = red[0];
  __syncthreads();
  float bm = bb;
  float sum = 0.f;
  for (int c = 0; c < nc; c++) {
    int i = t + c * 256;
    if (i < L) { rv[c] = __expf(rv[c] - bm); sum += rv[c]; }
  }
  red[t] = sum; __syncthreads();
  for (int st = 128; st > 0; st >>= 1) { if (t < st) red[t] += red[t + st]; __syncthreads(); }
  if (t == 0) bb = 1.f / red[0];
  __syncthreads();
  float inv = bb;
  for (int c = 0; c < nc; c++) {
    int i = t + c * 256;
    if (i < L) p[i] = rv[c] * inv;
  }
}

// ------- segment sum of point_feat: LDS accum, 8-deep load prefetch --------
__global__ __launch_bounds__(256) void segsum_k(const float* __restrict__ pf,
                                                const int* __restrict__ sv,
                                                float* __restrict__ part)
{
  __shared__ float acc[kS * DC];  // 65536 B (0 bank conflicts measured at DC=16)
  int t = threadIdx.x;
  for (int i = t; i < kS * DC; i += 256) acc[i] = 0.f;
  __syncthreads();
  int dc = blockIdx.x, sl = blockIdx.y, b = blockIdx.z;
  const int per = kN / NSLICE;
  int n0 = sl * per, n1 = n0 + per;
  int ld_ = t & (DC - 1), pg = t >> 4;   // 16 points per block-iteration
  for (int base = n0 + pg; base < n1; base += 16 * 8) {
    int s[8]; float v[8];
#pragma unroll
    for (int u = 0; u < 8; u++) {         // issue all 16 loads first
      int n = base + u * 16;
      bool ok = n < n1;
      s[u] = ok ? sv[b * kN + n] : -1;
      v[u] = ok ? pf[((long)b * kN + n) * kD + dc * DC + ld_] : 0.f;
    }
#pragma unroll
    for (int u = 0; u < 8; u++)           // then consume
      if (s[u] >= 0) atomicAdd(&acc[s[u] * DC + ld_], v[u]);
  }
  __syncthreads();
  float* outp = part + (((long)(b * NSLICE + sl) * DCH + dc) * (kS * DC));
  for (int i = t; i < kS * DC; i += 256) outp[i] = acc[i];
}

// ------- per-slice segment count + coord sums (LDS atomics, fused) ---------
__global__ __launch_bounds__(256) void segmeta_k(const float* __restrict__ pc,
                                                 const int* __restrict__ sv,
                                                 float* __restrict__ cpart,
                                                 float* __restrict__ csumpart)
{
  __shared__ float meta[kS * 4];  // cnt, x, y, z per segment
  int t = threadIdx.x;
  for (int i = t; i < kS * 4; i += 256) meta[i] = 0.f;
  __syncthreads();
  int sl = blockIdx.x, b = blockIdx.y;
  const int per = kN / NSLICE;
  int n0 = sl * per, n1 = n0 + per;
  for (int base = n0 + t; base < n1; base += 256 * 4) {
    int s[4]; float cx[4], cy[4], cz[4];
#pragma unroll
    for (int u = 0; u < 4; u++) {
      int n = base + u * 256;
      bool ok = n < n1;
      s[u] = ok ? sv[b * kN + n] : -1;
      long p = ((long)b * kN + n) * 3;
      cx[u] = ok ? pc[p + 0] : 0.f;
      cy[u] = ok ? pc[p + 1] : 0.f;
      cz[u] = ok ? pc[p + 2] : 0.f;
    }
#pragma unroll
    for (int u = 0; u < 4; u++)
      if (s[u] >= 0) {
        atomicAdd(&meta[s[u] * 4 + 0], 1.f);
        atomicAdd(&meta[s[u] * 4 + 1], cx[u]);
        atomicAdd(&meta[s[u] * 4 + 2], cy[u]);
        atomicAdd(&meta[s[u] * 4 + 3], cz[u]);
      }
  }
  __syncthreads();
  float* oc = cpart + (long)(b * NSLICE + sl) * kS;
  for (int i = t; i < kS; i += 256) oc[i] = meta[i * 4];
  float* os = csumpart + (long)(b * NSLICE + sl) * kS * 3;
  for (int i = t; i < kS * 3; i += 256) {
    int s2 = i / 3, j = i - s2 * 3;
    os[i] = meta[s2 * 4 + 1 + j];
  }
}

__global__ void cntfin_k(const float* __restrict__ cpart, float* __restrict__ counts)
{
  int i = blockIdx.x * 256 + threadIdx.x;
  if (i >= kB * kS) return;
  int b = i / kS, s = i - b * kS;
  float c = 0.f;
  for (int sl = 0; sl < NSLICE; sl++) c += cpart[(long)(b * NSLICE + sl) * kS + s];
  counts[i] = c;
}

__global__ void poolfin_k(const float* __restrict__ part, const float* __restrict__ counts,
                          float* __restrict__ pooled)
{
  long i = (long)blockIdx.x * 256 + threadIdx.x;
  if (i >= (long)kB * kS * kD) return;
  int d = (int)(i % kD);
  long bs = i / kD;
  int s = (int)(bs % kS), b = (int)(bs / kS);
  int dc = d / DC, dl = d - dc * DC;
  float sum = 0.f;
  for (int sl = 0; sl < NSLICE; sl++)
    sum += part[(((long)(b * NSLICE + sl) * DCH + dc) * (kS * DC)) + s * DC + dl];
  float c = counts[b * kS + s];
  pooled[i] = (c > 0.5f) ? sum / c : 0.f;
}

__global__ void coordfin_k(const float* __restrict__ csumpart, const float* __restrict__ counts,
                           float* __restrict__ pcoord)
{
  int i = blockIdx.x * 256 + threadIdx.x;
  if (i >= kB * kS * 3) return;
  int bs = i / 3, j = i - bs * 3;
  int b = bs / kS, s = bs - b * kS;
  float sum = 0.f;
  for (int sl = 0; sl < NSLICE; sl++)
    sum += csumpart[((long)(b * NSLICE + sl) * kS + s) * 3 + j];
  float c = counts[bs];
  pcoord[i] = (c > 0.5f) ? sum / c : 0.f;
}

// ---------------- consistency loss: mean((pf - pooled[sv])^2) --------------
__global__ __launch_bounds__(256) void closs_k(const float* __restrict__ pf,
                                               const int* __restrict__ sv,
                                               const float* __restrict__ pooled,
                                               float* __restrict__ outp)
{
  const long total = (long)kB * kN * (kD / 4);
  float a = 0.f;
  for (long i = (long)blockIdx.x * 256 + threadIdx.x; i < total; i += (long)gridDim.x * 256) {
    long pnt = i >> 6;
    int dc = (int)(i & 63);
    int b = (int)(pnt / kN);
    int s = sv[pnt];
    float4 v = ((const float4*)pf)[i];
    float4 m = ((const float4*)pooled)[((long)b * kS + s) * (kD / 4) + dc];
    float dx = v.x - m.x, dy = v.y - m.y, dz = v.z - m.z, dw = v.w - m.w;
    a += dx * dx + dy * dy + dz * dz + dw * dw;
  }
  __shared__ float red[256];
  red[threadIdx.x] = a; __syncthreads();
  for (int s = 128; s > 0; s >>= 1) { if (threadIdx.x < s) red[threadIdx.x] += red[threadIdx.x + s]; __syncthreads(); }
  if (threadIdx.x == 0) atomicAdd(outp, red[0]);
}

// ---------------- token build: cls+pos || tok+pos --------------------------
__global__ void build_k(const float* __restrict__ cls, const float* __restrict__ clspos,
                        const float* __restrict__ tok, const float* __restrict__ pos,
                        float* __restrict__ x, int T, int Tt, int posBatched)
{
  long i = (long)blockIdx.x * 256 + threadIdx.x;
  long tot = (long)kB * T * kD;
  if (i >= tot) return;
  int d = (int)(i % kD);
  long bt = i / kD;
  int t = (int)(bt % T), b = (int)(bt / T);
  float v;
  if (t < kC) v = cls[t * kD + d] + clspos[t * kD + d];
  else {
    int tt = t - kC;
    v = tok[((long)b * Tt + tt) * kD + d] +
        pos[((long)(posBatched ? b * Tt : 0) + tt) * kD + d];
  }
  x[i] = v;
}

// ---------------- token-sim loss from MHA1 probs (B,H,28,1044) -------------
__global__ __launch_bounds__(64) void simloss_k(const float* __restrict__ probs,
                                                float* __restrict__ accum)
{
  int b = blockIdx.x;
  __shared__ float sim[kC][kC];
  int t = threadIdx.x;
  for (int e = t; e < kC * kC; e += 64) {
    int i = e / kC, j = e - i * kC;
    float s = 0.f;
    for (int h = 0; h < kH; h++)
      s += probs[(((long)(b * kH + h)) * kTV + i) * kTX + j];
    sim[i][j] = s * (1.f / kH);
  }
  __syncthreads();
  float local = 0.f;
  if (t < kC) {
    int i = t;
    float mx = -1e30f;
    for (int j = 0; j < kC; j++) mx = fmaxf(mx, sim[i][j]);
    float se = 0.f;
    for (int j = 0; j < kC; j++) se += expf(sim[i][j] - mx);
    float dr = sim[i][i] - mx - logf(se);
    float mc = -1e30f;
    for (int j = 0; j < kC; j++) mc = fmaxf(mc, sim[j][i]);
    float sc = 0.f;
    for (int j = 0; j < kC; j++) sc += expf(sim[j][i] - mc);
    float dcl = sim[i][i] - mc - logf(sc);
    local = dr + dcl;
  }
  for (int o = 32; o > 0; o >>= 1) local += __shfl_down(local, o);
  if (t == 0) atomicAdd(accum, local * (-0.5f / kC));
}

// ---------------- small output kernels -------------------------------------
__global__ __launch_bounds__(64) void meanD_k(const float* __restrict__ x,
                                              float* __restrict__ o, int T)
{
  int bc = blockIdx.x;
  int b = bc / kC, c = bc - b * kC;
  const float* r = x + ((long)b * T + c) * kD;
  float s = 0.f;
  for (int d = threadIdx.x; d < kD; d += 64) s += r[d];
  for (int w = 32; w > 0; w >>= 1) s += __shfl_down(s, w);
  if (threadIdx.x == 0) o[bc] = s * (1.f / kD);
}

__global__ __launch_bounds__(64) void cross_k(const float* __restrict__ xv,
                                              const float* __restrict__ xw,
                                              float* __restrict__ o)
{
  int bc = blockIdx.x;
  int b = bc / kC, c = bc - b * kC;
  const float* rv = xv + ((long)b * kTX + c) * kD;
  const float* rw = xw + ((long)b * kTV + c) * kD;
  float s = 0.f;
  for (int d = threadIdx.x; d < kD; d += 64) s += 0.5f * (rv[d] + rw[d]);
  for (int w = 32; w > 0; w >>= 1) s += __shfl_down(s, w);
  if (threadIdx.x == 0) o[bc] = s * (1.f / kD);
}

__global__ __launch_bounds__(256) void cam3d_k(const float* __restrict__ vc,
                                               float* __restrict__ o)
{
  __shared__ float red[256];
  int bc = blockIdx.x;
  int b = bc / kC, c = bc - b * kC;
  float s = 0.f;
  for (int t = threadIdx.x; t < kS; t += 256) s += vc[((long)b * kS + t) * kC + c];
  red[threadIdx.x] = s; __syncthreads();
  for (int st = 128; st > 0; st >>= 1) { if (threadIdx.x < st) red[threadIdx.x] += red[threadIdx.x + st]; __syncthreads(); }
  if (threadIdx.x == 0) o[bc] = red[0] * (1.f / kS);
}

__global__ void meanv_k(const float* __restrict__ ivt, float* __restrict__ mv)
{
  int i = blockIdx.x * 256 + threadIdx.x;
  if (i >= kB * kD) return;
  int b = i / kD, d = i - b * kD;
  float s = 0.f;
  for (int v = 0; v < kV; v++) s += ivt[((long)b * kV + v) * kD + d];
  mv[i] = s * (1.f / kV);
}

__global__ __launch_bounds__(64) void cam2d_k(const float* __restrict__ mv,
                                              const float* __restrict__ w2,
                                              const float* __restrict__ b2,
                                              float* __restrict__ o)
{
  int bc = blockIdx.x;
  int b = bc / kC, c = bc - b * kC;
  float s = 0.f;
  for (int d = threadIdx.x; d < kD; d += 64) s += mv[b * kD + d] * w2[d * kC + c];
  for (int w = 32; w > 0; w >>= 1) s += __shfl_down(s, w);
  if (threadIdx.x == 0) o[bc] = s + b2[c];
}

__global__ void fin_k(const float* __restrict__ cl, const float* __restrict__ ts,
                      float* __restrict__ outp)
{
  outp[400] = cl[0] * (1.f / ((float)kB * (float)kN * (float)kD));
  outp[401] = ts[0] * (1.f / (kDepth * kB));
}

// ---------------- host-side dispatch helpers -------------------------------
static void gemm_disp(hipStream_t st, const float* A, const float* Bm, const float* bias,
                      const float* Res, float* C, int M, int N, int K,
                      int lda, int ldb, int ldc,
                      long sAb, long sAh, long sBb, long sBh, long sCb, long sCh,
                      int Z, int Hdim, float alpha, int act, bool trb, bool prelu)
{
  dim3 blk(256, 1, 1);
  long bigBlocks = (long)((M + 127) / 128) * ((N + 127) / 128) * Z;
  // big path only when it alone can fill the GPU; else 64x64 gives 4x blocks.
  bool big = (N >= 96) && (bigBlocks >= 384);
#define GARGS A, Bm, bias, Res, C, M, N, K, lda, ldb, ldc, sAb, sAh, sBb, sBh, sCb, sCh, Hdim, alpha
  if (big) {
    dim3 g((N + 127) / 128, (M + 127) / 128, Z);
    if (prelu)          gemm_k<128, 128, 8, 8, 0, false, true ><<<g, blk, 0, st>>>(GARGS);
    else if (trb)       gemm_k<128, 128, 8, 8, 0, true,  false><<<g, blk, 0, st>>>(GARGS);
    else if (act == 1)  gemm_k<128, 128, 8, 8, 1, false, false><<<g, blk, 0, st>>>(GARGS);
    else if (act == 2)  gemm_k<128, 128, 8, 8, 2, false, false><<<g, blk, 0, st>>>(GARGS);
    else                gemm_k<128, 128, 8, 8, 0, false, false><<<g, blk, 0, st>>>(GARGS);
  } else {
    dim3 g((N + 63) / 64, (M + 63) / 64, Z);
    if (prelu)          gemm_k<64, 64, 4, 4, 0, false, true ><<<g, blk, 0, st>>>(GARGS);
    else if (trb)       gemm_k<64, 64, 4, 4, 0, true,  false><<<g, blk, 0, st>>>(GARGS);
    else if (act == 1)  gemm_k<64, 64, 4, 4, 1, false, false><<<g, blk, 0, st>>>(GARGS);
    else if (act == 2)  gemm_k<64, 64, 4, 4, 2, false, false><<<g, blk, 0, st>>>(GARGS);
    else                gemm_k<64, 64, 4, 4, 0, false, false><<<g, blk, 0, st>>>(GARGS);
  }
#undef GARGS
}

static void linear(hipStream_t st, const float* A, const float* W, const float* bias,
                   const float* Res, float* C, int M, int N, int K, int act)
{
  gemm_disp(st, A, W, bias, Res, C, M, N, K, K, N, N, 0, 0, 0, 0, 0, 0, 1, 1, 1.f, act, false, false);
}

// materialized MHA: P = softmax(scale * Q K^T); O = P V
// qb: (B,Tq,ldq) head-major cols; kb/vb: (B,Tk,ldkv) head-major cols
static void attention(hipStream_t st, const float* qb, int ldq, const float* kb,
                      const float* vb, int ldkv, int Tq, int Tk, float* P, float* O)
{
  gemm_disp(st, qb, kb, nullptr, nullptr, P, Tq, Tk, kDH, ldq, ldkv, Tk,
            (long)Tq * ldq, kDH, (long)Tk * ldkv, kDH, (long)kH * Tq * Tk, (long)Tq * Tk,
            kB * kH, kH, kScale, 0, true, false);
  softmax_k<<<dim3(kB * kH * Tq), dim3(256), 0, st>>>(P, Tk);
  gemm_disp(st, P, vb, nullptr, nullptr, O, Tq, kDH, Tk, Tk, ldkv, kD,
            (long)kH * Tq * Tk, (long)Tq * Tk, (long)Tk * ldkv, kDH, (long)Tq * kD, kDH,
            kB * kH, kH, 1.f, 0, false, false);
}

}  // namespace

extern "C" void kernel_launch(void* const* d_in, const int* in_sizes, int n_in,
                              void* d_out, int out_size, void* d_ws, size_t ws_size,
                              hipStream_t stream)
{
  (void)in_sizes; (void)n_in; (void)out_size; (void)ws_size;
  const float* point_feat  = (const float*)d_in[0];
  const float* point_coord = (const float*)d_in[1];
  const float* ivt         = (const float*)d_in[2];
  const int*   sv          = (const int*)d_in[3];
  const float* cls_token   = (const float*)d_in[4];
  const float* cls_pos     = (const float*)d_in[5];
  const float* view_pos    = (const float*)d_in[6];
  const float* pos_w1 = (const float*)d_in[7];
  const float* pos_b1 = (const float*)d_in[8];
  const float* pos_w2 = (const float*)d_in[9];
  const float* pos_b2 = (const float*)d_in[10];
  const float* pos_w3 = (const float*)d_in[11];
  const float* pos_b3 = (const float*)d_in[12];
  const float* enc_qkv_w  = (const float*)d_in[13];
  const float* enc_qkv_b  = (const float*)d_in[14];
  const float* enc_proj_w = (const float*)d_in[15];
  const float* enc_proj_b = (const float*)d_in[16];
  const float* enc_ln1_g  = (const float*)d_in[17];
  const float* enc_ln1_b  = (const float*)d_in[18];
  const float* enc_ln2_g  = (const float*)d_in[19];
  const float* enc_ln2_b  = (const float*)d_in[20];
  const float* enc_mlp_w1 = (const float*)d_in[21];
  const float* enc_mlp_b1 = (const float*)d_in[22];
  const float* enc_mlp_w2 = (const float*)d_in[23];
  const float* enc_mlp_b2 = (const float*)d_in[24];
  const float* dec_q_w    = (const float*)d_in[25];
  const float* dec_q_b    = (const float*)d_in[26];
  const float* dec_kv_w   = (const float*)d_in[27];
  const float* dec_kv_b   = (const float*)d_in[28];
  const float* dec_proj_w = (const float*)d_in[29];
  const float* dec_proj_b = (const float*)d_in[30];
  const float* dec_lnq_g  = (const float*)d_in[31];
  const float* dec_lnq_b  = (const float*)d_in[32];
  const float* dec_lnkv_g = (const float*)d_in[33];
  const float* dec_lnkv_b = (const float*)d_in[34];
  const float* dec_ln2_g  = (const float*)d_in[35];
  const float* dec_ln2_b  = (const float*)d_in[36];
  const float* dec_mlp_w1 = (const float*)d_in[37];
  const float* dec_mlp_b1 = (const float*)d_in[38];
  const float* dec_mlp_w2 = (const float*)d_in[39];
  const float* dec_mlp_b2 = (const float*)d_in[40];
  const float* head2d_w = (const float*)d_in[41];
  const float* head2d_b = (const float*)d_in[42];
  const float* head3d_w = (const float*)d_in[43];
  const float* head3d_b = (const float*)d_in[44];
  float* out = (float*)d_out;

  float* w = (float*)d_ws;
  size_t off = 0;
  auto alloc = [&](size_t n) { float* p = w + off; off += n; return p; };

  // region A: segment-sum partials (early) aliased with attention scores (late)
  const size_t scores_sz = (size_t)kB * kH * kTX * kTX;            // 17.4M floats
  const size_t probs_sz  = (size_t)kB * kH * kTV * kTX;            // 468K floats
  float* regionA  = alloc(scores_sz + 2 * probs_sz);
  float* seg_part = regionA;        // dead before encoders run
  float* scores   = regionA;
  float* probs1   = regionA + scores_sz;
  float* probs2   = probs1 + probs_sz;

  float* cpart    = alloc((size_t)kB * NSLICE * kS);
  float* csumpart = alloc((size_t)kB * NSLICE * kS * 3);
  float* counts   = alloc((size_t)kB * kS);
  float* pooled   = alloc((size_t)kB * kS * kD);
  float* closs    = alloc(1);
  float* simacc   = alloc(1);
  float* pcoord   = alloc((size_t)kB * kS * 3);
  float* ph1      = alloc((size_t)kB * kS * kD);
  float* ph2      = alloc((size_t)kB * kS * kD);
  float* posb     = alloc((size_t)kB * kS * kD);
  float* x_view   = alloc((size_t)kB * kTV * kD);
  float* h_view   = alloc((size_t)kB * kTV * kD);
  float* qkv_view = alloc((size_t)kB * kTV * 3 * kD);
  float* o_view   = alloc((size_t)kB * kTV * kD);
  float* mlp_view = alloc((size_t)kB * kTV * kMH);
  float* x_vox    = alloc((size_t)kB * kTX * kD);
  float* h_vox    = alloc((size_t)kB * kTX * kD);
  float* qkv_vox  = alloc((size_t)kB * kTX * 3 * kD);
  float* o_vox    = alloc((size_t)kB * kTX * kD);
  float* mlp_vox  = alloc((size_t)kB * kTX * kMH);
  float* q_small  = alloc((size_t)kB * kTV * kD);
  float* kv_big   = alloc((size_t)kB * kTX * 2 * kD);
  float* q_big    = alloc((size_t)kB * kTX * kD);
  float* kv_small = alloc((size_t)kB * kTV * 2 * kD);
  float* meanv    = alloc((size_t)kB * kD);

  // zero the atomic accumulators (closs & simacc are adjacent allocs)
  hipMemsetAsync(closs, 0, 2 * sizeof(float), stream);

  // ---- point-cloud pooling + consistency loss ----
  segsum_k<<<dim3(DCH, NSLICE, kB), 256, 0, stream>>>(point_feat, sv, seg_part);
  segmeta_k<<<dim3(NSLICE, kB), 256, 0, stream>>>(point_coord, sv, cpart, csumpart);
  cntfin_k<<<dim3((kB * kS + 255) / 256), 256, 0, stream>>>(cpart, counts);
  poolfin_k<<<dim3((kB * kS * kD + 255) / 256), 256, 0, stream>>>(seg_part, counts, pooled);
  coordfin_k<<<dim3((kB * kS * 3 + 255) / 256), 256, 0, stream>>>(csumpart, counts, pcoord);
  closs_k<<<dim3(2048), 256, 0, stream>>>(point_feat, sv, pooled, closs);

  // ---- position MLP ----
  linear(stream, pcoord, pos_w1, pos_b1, nullptr, ph1, kB * kS, kD, 3, 1);
  linear(stream, ph1, pos_w2, pos_b2, nullptr, ph2, kB * kS, kD, kD, 1);
  linear(stream, ph2, pos_w3, pos_b3, nullptr, posb, kB * kS, kD, kD, 0);

  // ---- build token streams ----
  build_k<<<dim3(((unsigned)(kB * kTV * kD) + 255) / 256), 256, 0, stream>>>(
      cls_token, cls_pos, ivt, view_pos, x_view, kTV, kV, 0);
  build_k<<<dim3(((unsigned)(kB * kTX * kD) + 255) / 256), 256, 0, stream>>>(
      cls_token, cls_pos, pooled, posb, x_vox, kTX, kS, 1);

  // ---- encoders (e=0 view, e=1 vox) ----
  auto encoder = [&](float* x, int T, int e, float* h, float* qkv, float* o, float* mlp) {
    int M = kB * T;
    for (int dl = 0; dl < kDepth; dl++) {
      int wi = e * kDepth + dl;
      ln_k<<<dim3(M), 256, 0, stream>>>(x, enc_ln1_g + wi * kD, enc_ln1_b + wi * kD, h, M);
      linear(stream, h, enc_qkv_w + (long)wi * kD * 3 * kD, enc_qkv_b + (long)wi * 3 * kD,
             nullptr, qkv, M, 3 * kD, kD, 0);
      attention(stream, qkv, 3 * kD, qkv + kD, qkv + 2 * kD, 3 * kD, T, T, scores, o);
      linear(stream, o, enc_proj_w + (long)wi * kD * kD, enc_proj_b + (long)wi * kD, x, x, M, kD, kD, 0);
      ln_k<<<dim3(M), 256, 0, stream>>>(x, enc_ln2_g + wi * kD, enc_ln2_b + wi * kD, h, M);
      linear(stream, h, enc_mlp_w1 + (long)wi * kD * kMH, enc_mlp_b1 + (long)wi * kMH,
             nullptr, mlp, M, kMH, kD, 2);
      linear(stream, mlp, enc_mlp_w2 + (long)wi * kMH * kD, enc_mlp_b2 + (long)wi * kD, x, x, M, kD, kMH, 0);
    }
  };
  encoder(x_view, kTV, 0, h_view, qkv_view, o_view, mlp_view);
  meanD_k<<<dim3(kB * kC), 64, 0, stream>>>(x_view, out + 80, kTV);   // mct_logits_2d

  encoder(x_vox, kTX, 1, h_vox, qkv_vox, o_vox, mlp_vox);
  meanD_k<<<dim3(kB * kC), 64, 0, stream>>>(x_vox, out + 160, kTX);   // mct_logits_3d

  // voxel_cam = relu(vox_enc[:, C:]) @ head3d_w + b   (pre-decoder!)
  gemm_disp(stream, x_vox + (long)kC * kD, head3d_w, head3d_b, nullptr, out + 402,
            kS, kC, kD, kD, kC, kC,
            (long)kTX * kD, 0, 0, 0, (long)kS * kC, 0,
            kB, 1, 1.f, 0, false, true);
  cam3d_k<<<dim3(kB * kC), 256, 0, stream>>>(out + 402, out + 320);   // cam_logits_3d
  meanv_k<<<dim3((kB * kD + 255) / 256), 256, 0, stream>>>(ivt, meanv);
  cam2d_k<<<dim3(kB * kC), 64, 0, stream>>>(meanv, head2d_w, head2d_b, out + 240);  // cam_logits_2d

  // ---- cross decoder ----
  for (int dl = 0; dl < kDepth; dl++) {
    int w0 = dl, w1 = kDepth + dl;  // (branch, layer) flat index
    ln_k<<<dim3(kB * kTV), 256, 0, stream>>>(x_view, dec_lnq_g + w0 * kD, dec_lnq_b + w0 * kD, h_view, kB * kTV);
    ln_k<<<dim3(kB * kTX), 256, 0, stream>>>(x_vox, dec_lnkv_g + w0 * kD, dec_lnkv_b + w0 * kD, h_vox, kB * kTX);
    linear(stream, h_view, dec_q_w + (long)w0 * kD * kD, dec_q_b + (long)w0 * kD, nullptr, q_small, kB * kTV, kD, kD, 0);
    linear(stream, h_vox, dec_kv_w + (long)w0 * kD * 2 * kD, dec_kv_b + (long)w0 * 2 * kD, nullptr, kv_big, kB * kTX, 2 * kD, kD, 0);
    attention(stream, q_small, kD, kv_big, kv_big + kD, 2 * kD, kTV, kTX, probs1, o_view);
    simloss_k<<<dim3(kB), 64, 0, stream>>>(probs1, simacc);

    ln_k<<<dim3(kB * kTX), 256, 0, stream>>>(x_vox, dec_lnq_g + w1 * kD, dec_lnq_b + w1 * kD, h_vox, kB * kTX);
    ln_k<<<dim3(kB * kTV), 256, 0, stream>>>(x_view, dec_lnkv_g + w1 * kD, dec_lnkv_b + w1 * kD, h_view, kB * kTV);
    linear(stream, h_vox, dec_q_w + (long)w1 * kD * kD, dec_q_b + (long)w1 * kD, nullptr, q_big, kB * kTX, kD, kD, 0);
    linear(stream, h_view, dec_kv_w + (long)w1 * kD * 2 * kD, dec_kv_b + (long)w1 * 2 * kD, nullptr, kv_small, kB * kTV, 2 * kD, kD, 0);
    attention(stream, q_big, kD, kv_small, kv_small + kD, 2 * kD, kTX, kTV, probs2, o_vox);

    linear(stream, o_view, dec_proj_w + (long)w0 * kD * kD, dec_proj_b + (long)w0 * kD, x_view, x_view, kB * kTV, kD, kD, 0);
    linear(stream, o_vox, dec_proj_w + (long)w1 * kD * kD, dec_proj_b + (long)w1 * kD, x_vox, x_vox, kB * kTX, kD, kD, 0);

    ln_k<<<dim3(kB * kTV), 256, 0, stream>>>(x_view, dec_ln2_g + w0 * kD, dec_ln2_b + w0 * kD, h_view, kB * kTV);
    linear(stream, h_view, dec_mlp_w1 + (long)w0 * kD * kMH, dec_mlp_b1 + (long)w0 * kMH, nullptr, mlp_view, kB * kTV, kMH, kD, 2);
    linear(stream, mlp_view, dec_mlp_w2 + (long)w0 * kMH * kD, dec_mlp_b2 + (long)w0 * kD, x_view, x_view, kB * kTV, kD, kMH, 0);
    ln_k<<<dim3(kB * kTX), 256, 0, stream>>>(x_vox, dec_ln2_g + w1 * kD, dec_ln2_b + w1 * kD, h_vox, kB * kTX);
    linear(stream, h_vox, dec_mlp_w1 + (long)w1 * kD * kMH, dec_mlp_b1 + (long)w1 * kMH, nullptr, mlp_vox, kB * kTX, kMH, kD, 2);
    linear(stream, mlp_vox, dec_mlp_w2 + (long)w1 * kMH * kD, dec_mlp_b2 + (long)w1 * kD, x_vox, x_vox, kB * kTX, kD, kMH, 0);
  }

  cross_k<<<dim3(kB * kC), 64, 0, stream>>>(x_vox, x_view, out + 0);  // cross_mct_logits
  fin_k<<<dim3(1), 1, 0, stream>>>(closs, simacc, out);               // consistent + token_sim
}